// Round 1
// baseline (1081.062 us; speedup 1.0000x reference)
//
#include <hip/hip_runtime.h>

static constexpr int N_NODES = 100000;
static constexpr int N_EDGES = 3200000;
static constexpr int IN_DIM  = 512;
static constexpr int OUT_DIM = 128;

// ---------------- GEMM: xw = x @ W (fp32) ----------------
// Block: 256 threads, tile 32 rows x 128 cols, BK=64. 4x4 micro-tile/thread.
__global__ __launch_bounds__(256) void gemm_xw(const float* __restrict__ x,
                                               const float* __restrict__ W,
                                               float* __restrict__ xw) {
  __shared__ float xs[32][64];    // [row][k]  8KB
  __shared__ float ws[64][128];   // [k][col] 32KB
  const int tid  = threadIdx.x;
  const int row0 = blockIdx.x * 32;
  const int tr = (tid >> 5) << 2;   // 0,4,...,28
  const int tc = (tid & 31) << 2;   // 0,4,...,124

  float acc[4][4] = {};

  for (int kb = 0; kb < IN_DIM; kb += 64) {
    // stage x tile: 32 rows x 64 k (float4 per thread x2)
    {
      const int r  = tid >> 4;          // 0..15
      const int kk = (tid & 15) << 2;   // 0..60
#pragma unroll
      for (int p = 0; p < 2; ++p) {
        const int row = row0 + r + p * 16;
        float4 v = make_float4(0.f, 0.f, 0.f, 0.f);
        if (row < N_NODES)
          v = *reinterpret_cast<const float4*>(&x[(size_t)row * IN_DIM + kb + kk]);
        *reinterpret_cast<float4*>(&xs[r + p * 16][kk]) = v;
      }
    }
    // stage W tile: 64 k x 128 cols
    {
      const int k0 = tid >> 5;          // 0..7
      const int c  = (tid & 31) << 2;   // 0..124
#pragma unroll
      for (int p = 0; p < 8; ++p) {
        const int k = k0 + p * 8;
        *reinterpret_cast<float4*>(&ws[k][c]) =
            *reinterpret_cast<const float4*>(&W[(size_t)(kb + k) * OUT_DIM + c]);
      }
    }
    __syncthreads();

#pragma unroll 4
    for (int kk = 0; kk < 64; ++kk) {
      const float4 wv = *reinterpret_cast<const float4*>(&ws[kk][tc]);
      const float xa0 = xs[tr + 0][kk];
      const float xa1 = xs[tr + 1][kk];
      const float xa2 = xs[tr + 2][kk];
      const float xa3 = xs[tr + 3][kk];
      acc[0][0] += xa0 * wv.x; acc[0][1] += xa0 * wv.y; acc[0][2] += xa0 * wv.z; acc[0][3] += xa0 * wv.w;
      acc[1][0] += xa1 * wv.x; acc[1][1] += xa1 * wv.y; acc[1][2] += xa1 * wv.z; acc[1][3] += xa1 * wv.w;
      acc[2][0] += xa2 * wv.x; acc[2][1] += xa2 * wv.y; acc[2][2] += xa2 * wv.z; acc[2][3] += xa2 * wv.w;
      acc[3][0] += xa3 * wv.x; acc[3][1] += xa3 * wv.y; acc[3][2] += xa3 * wv.z; acc[3][3] += xa3 * wv.w;
    }
    __syncthreads();
  }

#pragma unroll
  for (int i = 0; i < 4; ++i) {
    const int row = row0 + tr + i;
    if (row < N_NODES) {
      float4 v = make_float4(acc[i][0], acc[i][1], acc[i][2], acc[i][3]);
      *reinterpret_cast<float4*>(&xw[(size_t)row * OUT_DIM + tc]) = v;
    }
  }
}

// ---------------- degree histogram ----------------
__global__ void count_deg(const int* __restrict__ col, int* __restrict__ deg) {
  int e = blockIdx.x * blockDim.x + threadIdx.x;
  const int stride = gridDim.x * blockDim.x;
  for (; e < N_EDGES; e += stride) atomicAdd(&deg[col[e]], 1);
}

__global__ void compute_dinv(const int* __restrict__ deg, float* __restrict__ dinv) {
  const int i = blockIdx.x * blockDim.x + threadIdx.x;
  if (i < N_NODES) dinv[i] = rsqrtf((float)deg[i] + 1.0f);
}

// ---------------- single-block exclusive scan over deg ----------------
__global__ __launch_bounds__(1024) void scan_offsets(const int* __restrict__ deg,
                                                     int* __restrict__ offs,
                                                     int* __restrict__ cursor) {
  __shared__ int part[1024];
  const int tid = threadIdx.x;
  const int chunk = (N_NODES + 1023) / 1024;  // 98
  const int start = tid * chunk;
  const int end = start < N_NODES ? min(start + chunk, N_NODES) : start;
  int s = 0;
  for (int i = start; i < end; ++i) s += deg[i];
  part[tid] = s;
  __syncthreads();
  for (int d = 1; d < 1024; d <<= 1) {
    int t = (tid >= d) ? part[tid - d] : 0;
    __syncthreads();
    part[tid] += t;
    __syncthreads();
  }
  int run = part[tid] - s;  // exclusive prefix
  for (int i = start; i < end; ++i) {
    offs[i] = run;
    cursor[i] = run;
    run += deg[i];
  }
  if (tid == 1023) offs[N_NODES] = part[1023];
}

// ---------------- bucket edges by destination ----------------
__global__ void bucket_edges(const int* __restrict__ row, const int* __restrict__ col,
                             int* __restrict__ cursor, int* __restrict__ brow) {
  int e = blockIdx.x * blockDim.x + threadIdx.x;
  const int stride = gridDim.x * blockDim.x;
  for (; e < N_EDGES; e += stride) {
    const int c = col[e];
    const int slot = atomicAdd(&cursor[c], 1);
    brow[slot] = row[e];
  }
}

// ---------------- gather: one wave per destination node ----------------
__global__ __launch_bounds__(256) void gather_out(const float* __restrict__ xw,
                                                  const float* __restrict__ dinv,
                                                  const int* __restrict__ offs,
                                                  const int* __restrict__ brow,
                                                  const float* __restrict__ bias,
                                                  float* __restrict__ out) {
  const int lane = threadIdx.x & 63;
  const int node = blockIdx.x * (blockDim.x >> 6) + (threadIdx.x >> 6);
  if (node >= N_NODES) return;
  const float di = dinv[node];
  const int c0 = lane * 2;

  float2 acc;
  {
    const float2 v = *reinterpret_cast<const float2*>(&xw[(size_t)node * OUT_DIM + c0]);
    const float s = di * di;  // self-loop norm
    acc.x = v.x * s;
    acc.y = v.y * s;
  }

  const int e0 = offs[node];
  const int e1 = offs[node + 1];
  int e = e0;
  int r_next = (e < e1) ? brow[e] : 0;
  while (e < e1) {
    const int r = r_next;
    ++e;
    if (e < e1) r_next = brow[e];  // prefetch next edge index
    const float nr = dinv[r] * di;
    const float2 v = *reinterpret_cast<const float2*>(&xw[(size_t)r * OUT_DIM + c0]);
    acc.x += v.x * nr;
    acc.y += v.y * nr;
  }

  const float2 bb = *reinterpret_cast<const float2*>(&bias[c0]);
  float2 o;
  o.x = acc.x + bb.x;
  o.y = acc.y + bb.y;
  *reinterpret_cast<float2*>(&out[(size_t)node * OUT_DIM + c0]) = o;
}

extern "C" void kernel_launch(void* const* d_in, const int* in_sizes, int n_in,
                              void* d_out, int out_size, void* d_ws, size_t ws_size,
                              hipStream_t stream) {
  const float* x    = (const float*)d_in[0];
  const int*   eidx = (const int*)d_in[1];   // [2, E] row-major int32
  const float* W    = (const float*)d_in[2];
  const float* b    = (const float*)d_in[3];
  float* out = (float*)d_out;

  const int* erow = eidx;            // sources
  const int* ecol = eidx + N_EDGES;  // destinations

  char* ws = (char*)d_ws;
  size_t off = 0;
  auto alloc = [&](size_t bytes) -> void* {
    void* p = ws + off;
    off = (off + bytes + 255) & ~(size_t)255;
    return p;
  };
  float* xw     = (float*)alloc((size_t)N_NODES * OUT_DIM * sizeof(float)); // 51.2MB
  float* dinv   = (float*)alloc((size_t)N_NODES * sizeof(float));
  int*   deg    = (int*)alloc((size_t)N_NODES * sizeof(int));
  int*   offs   = (int*)alloc((size_t)(N_NODES + 1) * sizeof(int));
  int*   cursor = (int*)alloc((size_t)N_NODES * sizeof(int));
  int*   brow   = (int*)alloc((size_t)N_EDGES * sizeof(int));               // 12.8MB

  hipMemsetAsync(deg, 0, (size_t)N_NODES * sizeof(int), stream);

  gemm_xw<<<(N_NODES + 31) / 32, 256, 0, stream>>>(x, W, xw);
  count_deg<<<2048, 256, 0, stream>>>(ecol, deg);
  compute_dinv<<<(N_NODES + 255) / 256, 256, 0, stream>>>(deg, dinv);
  scan_offsets<<<1, 1024, 0, stream>>>(deg, offs, cursor);
  bucket_edges<<<2048, 256, 0, stream>>>(erow, ecol, cursor, brow);
  gather_out<<<(N_NODES + 3) / 4, 256, 0, stream>>>(xw, dinv, offs, brow, b, out);
}

// Round 2
// 836.387 us; speedup vs baseline: 1.2925x; 1.2925x over previous
//
#include <hip/hip_runtime.h>

using short8 = __attribute__((ext_vector_type(8))) short;
using f32x4  = __attribute__((ext_vector_type(4))) float;

static constexpr int N_NODES = 100000;
static constexpr int N_EDGES = 3200000;
static constexpr int IN_DIM  = 512;
static constexpr int OUT_DIM = 128;

__device__ __forceinline__ short f2bf(float f) {
  unsigned u = __builtin_bit_cast(unsigned, f);
  u = (u + 0x7FFFu + ((u >> 16) & 1u)) >> 16;  // RNE
  return (short)u;
}

// ---------------- W [512][128] f32  ->  WT [128][512] bf16 ----------------
__global__ __launch_bounds__(256) void cast_WT(const float* __restrict__ W,
                                               short* __restrict__ WT) {
  const int idx = blockIdx.x * 256 + threadIdx.x;  // 65536 total
  const int c = idx >> 9, k = idx & 511;
  WT[(size_t)c * 512 + k] = f2bf(W[(size_t)k * 128 + c]);
}

// ---------------- MFMA GEMM: xw = x @ W (bf16 in, fp32 out) ----------------
// Block: 256 thr = 4 waves (2x2 over rows32 x cols64). Tile 64 rows x 128 cols.
// Full K=512 of the A-tile staged once in 64KB LDS (XOR-swizzled rows).
// B fragments read per-lane from L2-resident WT.
__global__ __launch_bounds__(256) void gemm_mfma(const float* __restrict__ x,
                                                 const short* __restrict__ WT,
                                                 float* __restrict__ xw) {
  __shared__ short As[64 * 512];  // 64KB, row-major, byte^((row&7)<<4) swizzle
  const int tid  = threadIdx.x;
  const int row0 = blockIdx.x * 64;

  // stage + cast: 256 thr x 16 iters x 8 floats (coalesced), swizzled ds_write_b128
#pragma unroll
  for (int it = 0; it < 16; ++it) {
    const int flat = it * 2048 + tid * 8;  // float index in 64x512 tile
    const int r = flat >> 9;
    const int k = flat & 511;
    short8 sv = {};
    if (row0 + r < N_NODES) {
      const float* s = &x[(size_t)(row0 + r) * IN_DIM + k];
      const float4 f0 = *reinterpret_cast<const float4*>(s);
      const float4 f1 = *reinterpret_cast<const float4*>(s + 4);
      sv[0] = f2bf(f0.x); sv[1] = f2bf(f0.y); sv[2] = f2bf(f0.z); sv[3] = f2bf(f0.w);
      sv[4] = f2bf(f1.x); sv[5] = f2bf(f1.y); sv[6] = f2bf(f1.z); sv[7] = f2bf(f1.w);
    }
    const int byte = (k * 2) ^ ((r & 7) << 4);
    *reinterpret_cast<short8*>(reinterpret_cast<char*>(As) + r * 1024 + byte) = sv;
  }
  __syncthreads();

  const int l  = tid & 63;
  const int w  = tid >> 6;
  const int wr = w >> 1, wc = w & 1;
  const int lr = l & 15;   // A row / B col within fragment
  const int lk = l >> 4;   // k-group: k = lk*8 + j

  const int arow0 = wr * 32 + lr;
  const int arow1 = arow0 + 16;
  const char* a0base = reinterpret_cast<const char*>(As) + arow0 * 1024;
  const char* a1base = reinterpret_cast<const char*>(As) + arow1 * 1024;
  const int rx0 = (arow0 & 7) << 4;
  const int rx1 = (arow1 & 7) << 4;

  const short8* b0 = reinterpret_cast<const short8*>(WT + (size_t)(wc * 64 +  0 + lr) * 512) + lk;
  const short8* b1 = reinterpret_cast<const short8*>(WT + (size_t)(wc * 64 + 16 + lr) * 512) + lk;
  const short8* b2 = reinterpret_cast<const short8*>(WT + (size_t)(wc * 64 + 32 + lr) * 512) + lk;
  const short8* b3 = reinterpret_cast<const short8*>(WT + (size_t)(wc * 64 + 48 + lr) * 512) + lk;

  f32x4 acc[2][4] = {};

#pragma unroll 4
  for (int ks = 0; ks < 16; ++ks) {
    const int kb = ks * 64 + lk * 16;  // byte offset in row
    const short8 a0 = *reinterpret_cast<const short8*>(a0base + (kb ^ rx0));
    const short8 a1 = *reinterpret_cast<const short8*>(a1base + (kb ^ rx1));
    const short8 bb0 = b0[ks * 4];
    const short8 bb1 = b1[ks * 4];
    const short8 bb2 = b2[ks * 4];
    const short8 bb3 = b3[ks * 4];
    acc[0][0] = __builtin_amdgcn_mfma_f32_16x16x32_bf16(a0, bb0, acc[0][0], 0, 0, 0);
    acc[0][1] = __builtin_amdgcn_mfma_f32_16x16x32_bf16(a0, bb1, acc[0][1], 0, 0, 0);
    acc[0][2] = __builtin_amdgcn_mfma_f32_16x16x32_bf16(a0, bb2, acc[0][2], 0, 0, 0);
    acc[0][3] = __builtin_amdgcn_mfma_f32_16x16x32_bf16(a0, bb3, acc[0][3], 0, 0, 0);
    acc[1][0] = __builtin_amdgcn_mfma_f32_16x16x32_bf16(a1, bb0, acc[1][0], 0, 0, 0);
    acc[1][1] = __builtin_amdgcn_mfma_f32_16x16x32_bf16(a1, bb1, acc[1][1], 0, 0, 0);
    acc[1][2] = __builtin_amdgcn_mfma_f32_16x16x32_bf16(a1, bb2, acc[1][2], 0, 0, 0);
    acc[1][3] = __builtin_amdgcn_mfma_f32_16x16x32_bf16(a1, bb3, acc[1][3], 0, 0, 0);
  }

  // C/D: col = lane&15, row = (lane>>4)*4 + reg  (verified m89/m91)
#pragma unroll
  for (int m = 0; m < 2; ++m) {
    const int rbase = row0 + wr * 32 + m * 16 + (l >> 4) * 4;
#pragma unroll
    for (int j = 0; j < 4; ++j) {
      const int row = rbase + j;
      if (row < N_NODES) {
        float* o = &xw[(size_t)row * OUT_DIM + wc * 64 + lr];
        o[0]  = acc[m][0][j];
        o[16] = acc[m][1][j];
        o[32] = acc[m][2][j];
        o[48] = acc[m][3][j];
      }
    }
  }
}

// ---------------- histogram + slot assignment ----------------
__global__ void count_slot(const int* __restrict__ col, int* __restrict__ deg,
                           int* __restrict__ slot) {
  int e = blockIdx.x * blockDim.x + threadIdx.x;
  const int stride = gridDim.x * blockDim.x;
  for (; e < N_EDGES; e += stride) slot[e] = atomicAdd(&deg[col[e]], 1);
}

__global__ void count_only(const int* __restrict__ col, int* __restrict__ deg) {
  int e = blockIdx.x * blockDim.x + threadIdx.x;
  const int stride = gridDim.x * blockDim.x;
  for (; e < N_EDGES; e += stride) atomicAdd(&deg[col[e]], 1);
}

// ---------------- single-block exclusive scan + dinv ----------------
__global__ __launch_bounds__(1024) void scan_offsets(const int* __restrict__ deg,
                                                     int* __restrict__ offs,
                                                     int* __restrict__ cursor,
                                                     float* __restrict__ dinv) {
  __shared__ int part[1024];
  const int tid = threadIdx.x;
  const int chunk = (N_NODES + 1023) / 1024;
  const int start = tid * chunk;
  const int end = start < N_NODES ? min(start + chunk, N_NODES) : start;
  int s = 0;
  for (int i = start; i < end; ++i) s += deg[i];
  part[tid] = s;
  __syncthreads();
  for (int d = 1; d < 1024; d <<= 1) {
    int t = (tid >= d) ? part[tid - d] : 0;
    __syncthreads();
    part[tid] += t;
    __syncthreads();
  }
  int run = part[tid] - s;
  for (int i = start; i < end; ++i) {
    offs[i] = run;
    cursor[i] = run;
    dinv[i] = rsqrtf((float)deg[i] + 1.0f);
    run += deg[i];
  }
  if (tid == 1023) offs[N_NODES] = part[1023];
}

// ---------------- bucket: atomic-free permutation write ----------------
__global__ void bucket_noatomic(const int* __restrict__ row, const int* __restrict__ col,
                                const int* __restrict__ slot, const int* __restrict__ offs,
                                int* __restrict__ brow) {
  int e = blockIdx.x * blockDim.x + threadIdx.x;
  const int stride = gridDim.x * blockDim.x;
  for (; e < N_EDGES; e += stride) brow[offs[col[e]] + slot[e]] = row[e];
}

// fallback (ws too small for slot buffer): atomic-cursor bucketing
__global__ void bucket_atomic(const int* __restrict__ row, const int* __restrict__ col,
                              int* __restrict__ cursor, int* __restrict__ brow) {
  int e = blockIdx.x * blockDim.x + threadIdx.x;
  const int stride = gridDim.x * blockDim.x;
  for (; e < N_EDGES; e += stride) {
    const int c = col[e];
    const int s = atomicAdd(&cursor[c], 1);
    brow[s] = row[e];
  }
}

// ---------------- gather: one wave per destination node ----------------
__global__ __launch_bounds__(256) void gather_out(const float* __restrict__ xw,
                                                  const float* __restrict__ dinv,
                                                  const int* __restrict__ offs,
                                                  const int* __restrict__ brow,
                                                  const float* __restrict__ bias,
                                                  float* __restrict__ out) {
  const int lane = threadIdx.x & 63;
  const int node = blockIdx.x * (blockDim.x >> 6) + (threadIdx.x >> 6);
  if (node >= N_NODES) return;
  const float di = dinv[node];
  const int c0 = lane * 2;

  float2 acc;
  {
    const float2 v = *reinterpret_cast<const float2*>(&xw[(size_t)node * OUT_DIM + c0]);
    const float s = di * di;
    acc.x = v.x * s;
    acc.y = v.y * s;
  }

  int e = offs[node];
  const int e1 = offs[node + 1];
  for (; e + 2 <= e1; e += 2) {
    const int r0 = brow[e];
    const int r1 = brow[e + 1];
    const float n0 = dinv[r0] * di;
    const float n1 = dinv[r1] * di;
    const float2 v0 = *reinterpret_cast<const float2*>(&xw[(size_t)r0 * OUT_DIM + c0]);
    const float2 v1 = *reinterpret_cast<const float2*>(&xw[(size_t)r1 * OUT_DIM + c0]);
    acc.x += v0.x * n0 + v1.x * n1;
    acc.y += v0.y * n0 + v1.y * n1;
  }
  if (e < e1) {
    const int r = brow[e];
    const float nr = dinv[r] * di;
    const float2 v = *reinterpret_cast<const float2*>(&xw[(size_t)r * OUT_DIM + c0]);
    acc.x += v.x * nr;
    acc.y += v.y * nr;
  }

  const float2 bb = *reinterpret_cast<const float2*>(&bias[c0]);
  float2 o;
  o.x = acc.x + bb.x;
  o.y = acc.y + bb.y;
  *reinterpret_cast<float2*>(&out[(size_t)node * OUT_DIM + c0]) = o;
}

extern "C" void kernel_launch(void* const* d_in, const int* in_sizes, int n_in,
                              void* d_out, int out_size, void* d_ws, size_t ws_size,
                              hipStream_t stream) {
  const float* x    = (const float*)d_in[0];
  const int*   eidx = (const int*)d_in[1];
  const float* W    = (const float*)d_in[2];
  const float* b    = (const float*)d_in[3];
  float* out = (float*)d_out;

  const int* erow = eidx;            // sources
  const int* ecol = eidx + N_EDGES;  // destinations

  char* ws = (char*)d_ws;
  size_t off = 0;
  auto alloc = [&](size_t bytes) -> void* {
    void* p = ws + off;
    off = (off + bytes + 255) & ~(size_t)255;
    return p;
  };
  float* xw     = (float*)alloc((size_t)N_NODES * OUT_DIM * sizeof(float));  // 51.2MB
  short* WT     = (short*)alloc((size_t)OUT_DIM * IN_DIM * sizeof(short));   // 128KB
  float* dinv   = (float*)alloc((size_t)N_NODES * sizeof(float));
  int*   deg    = (int*)alloc((size_t)N_NODES * sizeof(int));
  int*   offs   = (int*)alloc((size_t)(N_NODES + 1) * sizeof(int));
  int*   cursor = (int*)alloc((size_t)N_NODES * sizeof(int));
  int*   brow   = (int*)alloc((size_t)N_EDGES * sizeof(int));                // 12.8MB
  size_t off_no_slot = off;
  int*   slot   = (int*)alloc((size_t)N_EDGES * sizeof(int));                // 12.8MB
  const bool two_pass = (off <= ws_size);
  (void)off_no_slot;

  hipMemsetAsync(deg, 0, (size_t)N_NODES * sizeof(int), stream);

  cast_WT<<<256, 256, 0, stream>>>(W, WT);

  if (two_pass) {
    count_slot<<<2048, 256, 0, stream>>>(ecol, deg, slot);
    scan_offsets<<<1, 1024, 0, stream>>>(deg, offs, cursor, dinv);
    bucket_noatomic<<<2048, 256, 0, stream>>>(erow, ecol, slot, offs, brow);
  } else {
    count_only<<<2048, 256, 0, stream>>>(ecol, deg);
    scan_offsets<<<1, 1024, 0, stream>>>(deg, offs, cursor, dinv);
    bucket_atomic<<<2048, 256, 0, stream>>>(erow, ecol, cursor, brow);
  }

  gemm_mfma<<<(N_NODES + 63) / 64, 256, 0, stream>>>(x, WT, xw);
  gather_out<<<(N_NODES + 3) / 4, 256, 0, stream>>>(xw, dinv, offs, brow, b, out);
}

// Round 3
// 569.752 us; speedup vs baseline: 1.8974x; 1.4680x over previous
//
#include <hip/hip_runtime.h>

using short8 = __attribute__((ext_vector_type(8))) short;
using f32x4  = __attribute__((ext_vector_type(4))) float;

static constexpr int N_NODES = 100000;
static constexpr int N_EDGES = 3200000;
static constexpr int IN_DIM  = 512;
static constexpr int OUT_DIM = 128;
static constexpr int NSCAN_BLOCKS = (N_NODES + 255) / 256;  // 391

__device__ __forceinline__ short f2bf(float f) {
  unsigned u = __builtin_bit_cast(unsigned, f);
  u = (u + 0x7FFFu + ((u >> 16) & 1u)) >> 16;  // RNE
  return (short)u;
}

// ---------------- W [512][128] f32  ->  WT [128][512] bf16 ----------------
__global__ __launch_bounds__(256) void cast_WT(const float* __restrict__ W,
                                               short* __restrict__ WT) {
  const int idx = blockIdx.x * 256 + threadIdx.x;  // 65536 total
  const int c = idx >> 9, k = idx & 511;
  WT[(size_t)c * 512 + k] = f2bf(W[(size_t)k * 128 + c]);
}

// ---------------- MFMA GEMM: xw = x @ W (bf16 in, fp32 out) ----------------
__global__ __launch_bounds__(256) void gemm_mfma(const float* __restrict__ x,
                                                 const short* __restrict__ WT,
                                                 float* __restrict__ xw) {
  __shared__ short As[64 * 512];  // 64KB, row-major, byte^((row&7)<<4) swizzle
  const int tid  = threadIdx.x;
  const int row0 = blockIdx.x * 64;

#pragma unroll
  for (int it = 0; it < 16; ++it) {
    const int flat = it * 2048 + tid * 8;
    const int r = flat >> 9;
    const int k = flat & 511;
    short8 sv = {};
    if (row0 + r < N_NODES) {
      const float* s = &x[(size_t)(row0 + r) * IN_DIM + k];
      const float4 f0 = *reinterpret_cast<const float4*>(s);
      const float4 f1 = *reinterpret_cast<const float4*>(s + 4);
      sv[0] = f2bf(f0.x); sv[1] = f2bf(f0.y); sv[2] = f2bf(f0.z); sv[3] = f2bf(f0.w);
      sv[4] = f2bf(f1.x); sv[5] = f2bf(f1.y); sv[6] = f2bf(f1.z); sv[7] = f2bf(f1.w);
    }
    const int byte = (k * 2) ^ ((r & 7) << 4);
    *reinterpret_cast<short8*>(reinterpret_cast<char*>(As) + r * 1024 + byte) = sv;
  }
  __syncthreads();

  const int l  = tid & 63;
  const int w  = tid >> 6;
  const int wr = w >> 1, wc = w & 1;
  const int lr = l & 15;
  const int lk = l >> 4;

  const int arow0 = wr * 32 + lr;
  const int arow1 = arow0 + 16;
  const char* a0base = reinterpret_cast<const char*>(As) + arow0 * 1024;
  const char* a1base = reinterpret_cast<const char*>(As) + arow1 * 1024;
  const int rx0 = (arow0 & 7) << 4;
  const int rx1 = (arow1 & 7) << 4;

  const short8* b0 = reinterpret_cast<const short8*>(WT + (size_t)(wc * 64 +  0 + lr) * 512) + lk;
  const short8* b1 = reinterpret_cast<const short8*>(WT + (size_t)(wc * 64 + 16 + lr) * 512) + lk;
  const short8* b2 = reinterpret_cast<const short8*>(WT + (size_t)(wc * 64 + 32 + lr) * 512) + lk;
  const short8* b3 = reinterpret_cast<const short8*>(WT + (size_t)(wc * 64 + 48 + lr) * 512) + lk;

  f32x4 acc[2][4] = {};

#pragma unroll 4
  for (int ks = 0; ks < 16; ++ks) {
    const int kb = ks * 64 + lk * 16;
    const short8 a0 = *reinterpret_cast<const short8*>(a0base + (kb ^ rx0));
    const short8 a1 = *reinterpret_cast<const short8*>(a1base + (kb ^ rx1));
    const short8 bb0 = b0[ks * 4];
    const short8 bb1 = b1[ks * 4];
    const short8 bb2 = b2[ks * 4];
    const short8 bb3 = b3[ks * 4];
    acc[0][0] = __builtin_amdgcn_mfma_f32_16x16x32_bf16(a0, bb0, acc[0][0], 0, 0, 0);
    acc[0][1] = __builtin_amdgcn_mfma_f32_16x16x32_bf16(a0, bb1, acc[0][1], 0, 0, 0);
    acc[0][2] = __builtin_amdgcn_mfma_f32_16x16x32_bf16(a0, bb2, acc[0][2], 0, 0, 0);
    acc[0][3] = __builtin_amdgcn_mfma_f32_16x16x32_bf16(a0, bb3, acc[0][3], 0, 0, 0);
    acc[1][0] = __builtin_amdgcn_mfma_f32_16x16x32_bf16(a1, bb0, acc[1][0], 0, 0, 0);
    acc[1][1] = __builtin_amdgcn_mfma_f32_16x16x32_bf16(a1, bb1, acc[1][1], 0, 0, 0);
    acc[1][2] = __builtin_amdgcn_mfma_f32_16x16x32_bf16(a1, bb2, acc[1][2], 0, 0, 0);
    acc[1][3] = __builtin_amdgcn_mfma_f32_16x16x32_bf16(a1, bb3, acc[1][3], 0, 0, 0);
  }

#pragma unroll
  for (int m = 0; m < 2; ++m) {
    const int rbase = row0 + wr * 32 + m * 16 + (l >> 4) * 4;
#pragma unroll
    for (int j = 0; j < 4; ++j) {
      const int row = rbase + j;
      if (row < N_NODES) {
        float* o = &xw[(size_t)row * OUT_DIM + wc * 64 + lr];
        o[0]  = acc[m][0][j];
        o[16] = acc[m][1][j];
        o[32] = acc[m][2][j];
        o[48] = acc[m][3][j];
      }
    }
  }
}

// ---------------- histogram + slot assignment ----------------
__global__ void count_slot(const int* __restrict__ col, int* __restrict__ deg,
                           int* __restrict__ slot) {
  int e = blockIdx.x * blockDim.x + threadIdx.x;
  const int stride = gridDim.x * blockDim.x;
  for (; e < N_EDGES; e += stride) slot[e] = atomicAdd(&deg[col[e]], 1);
}

// ---------------- 3-phase device-wide exclusive scan over deg ----------------
__global__ __launch_bounds__(256) void block_sums(const int* __restrict__ deg,
                                                  int* __restrict__ bsum) {
  const int i = blockIdx.x * 256 + threadIdx.x;
  int v = (i < N_NODES) ? deg[i] : 0;
#pragma unroll
  for (int d = 1; d < 64; d <<= 1) v += __shfl_xor(v, d);
  __shared__ int part[4];
  if ((threadIdx.x & 63) == 0) part[threadIdx.x >> 6] = v;
  __syncthreads();
  if (threadIdx.x == 0) bsum[blockIdx.x] = part[0] + part[1] + part[2] + part[3];
}

__global__ __launch_bounds__(512) void scan_bsums(int* __restrict__ bsum,
                                                  int* __restrict__ bpre,
                                                  int* __restrict__ offs) {
  __shared__ int sh[512];
  const int tid = threadIdx.x;
  int v = (tid < NSCAN_BLOCKS) ? bsum[tid] : 0;
  sh[tid] = v;
  __syncthreads();
  for (int d = 1; d < 512; d <<= 1) {
    int t = (tid >= d) ? sh[tid - d] : 0;
    __syncthreads();
    sh[tid] += t;
    __syncthreads();
  }
  if (tid < NSCAN_BLOCKS) bpre[tid] = sh[tid] - v;  // exclusive
  if (tid == NSCAN_BLOCKS - 1) offs[N_NODES] = sh[tid];
}

__global__ __launch_bounds__(256) void scan_final(const int* __restrict__ deg,
                                                  const int* __restrict__ bpre,
                                                  int* __restrict__ offs,
                                                  int* __restrict__ cursor,
                                                  float* __restrict__ dinv) {
  __shared__ int sh[256];
  const int tid = threadIdx.x;
  const int i = blockIdx.x * 256 + tid;
  const int d0 = (i < N_NODES) ? deg[i] : 0;
  sh[tid] = d0;
  __syncthreads();
  for (int d = 1; d < 256; d <<= 1) {
    int t = (tid >= d) ? sh[tid - d] : 0;
    __syncthreads();
    sh[tid] += t;
    __syncthreads();
  }
  if (i < N_NODES) {
    const int off = bpre[blockIdx.x] + sh[tid] - d0;  // exclusive prefix
    offs[i] = off;
    cursor[i] = off;
    dinv[i] = rsqrtf((float)d0 + 1.0f);
  }
}

// ---------------- bucket: atomic-free permutation write ----------------
__global__ void bucket_noatomic(const int* __restrict__ row, const int* __restrict__ col,
                                const int* __restrict__ slot, const int* __restrict__ offs,
                                int* __restrict__ brow) {
  int e = blockIdx.x * blockDim.x + threadIdx.x;
  const int stride = gridDim.x * blockDim.x;
  for (; e < N_EDGES; e += stride) brow[offs[col[e]] + slot[e]] = row[e];
}

// fallback (ws too small for slot buffer): atomic-cursor bucketing
__global__ void count_only(const int* __restrict__ col, int* __restrict__ deg) {
  int e = blockIdx.x * blockDim.x + threadIdx.x;
  const int stride = gridDim.x * blockDim.x;
  for (; e < N_EDGES; e += stride) atomicAdd(&deg[col[e]], 1);
}

__global__ void bucket_atomic(const int* __restrict__ row, const int* __restrict__ col,
                              int* __restrict__ cursor, int* __restrict__ brow) {
  int e = blockIdx.x * blockDim.x + threadIdx.x;
  const int stride = gridDim.x * blockDim.x;
  for (; e < N_EDGES; e += stride) {
    const int c = col[e];
    const int s = atomicAdd(&cursor[c], 1);
    brow[s] = row[e];
  }
}

// ---------------- gather: one wave per destination node ----------------
__global__ __launch_bounds__(256) void gather_out(const float* __restrict__ xw,
                                                  const float* __restrict__ dinv,
                                                  const int* __restrict__ offs,
                                                  const int* __restrict__ brow,
                                                  const float* __restrict__ bias,
                                                  float* __restrict__ out) {
  const int lane = threadIdx.x & 63;
  const int node = blockIdx.x * (blockDim.x >> 6) + (threadIdx.x >> 6);
  if (node >= N_NODES) return;
  const float di = dinv[node];
  const int c0 = lane * 2;

  float2 acc;
  {
    const float2 v = *reinterpret_cast<const float2*>(&xw[(size_t)node * OUT_DIM + c0]);
    const float s = di * di;
    acc.x = v.x * s;
    acc.y = v.y * s;
  }

  int e = offs[node];
  const int e1 = offs[node + 1];
  for (; e + 2 <= e1; e += 2) {
    const int r0 = brow[e];
    const int r1 = brow[e + 1];
    const float n0 = dinv[r0] * di;
    const float n1 = dinv[r1] * di;
    const float2 v0 = *reinterpret_cast<const float2*>(&xw[(size_t)r0 * OUT_DIM + c0]);
    const float2 v1 = *reinterpret_cast<const float2*>(&xw[(size_t)r1 * OUT_DIM + c0]);
    acc.x += v0.x * n0 + v1.x * n1;
    acc.y += v0.y * n0 + v1.y * n1;
  }
  if (e < e1) {
    const int r = brow[e];
    const float nr = dinv[r] * di;
    const float2 v = *reinterpret_cast<const float2*>(&xw[(size_t)r * OUT_DIM + c0]);
    acc.x += v.x * nr;
    acc.y += v.y * nr;
  }

  const float2 bb = *reinterpret_cast<const float2*>(&bias[c0]);
  float2 o;
  o.x = acc.x + bb.x;
  o.y = acc.y + bb.y;
  *reinterpret_cast<float2*>(&out[(size_t)node * OUT_DIM + c0]) = o;
}

extern "C" void kernel_launch(void* const* d_in, const int* in_sizes, int n_in,
                              void* d_out, int out_size, void* d_ws, size_t ws_size,
                              hipStream_t stream) {
  const float* x    = (const float*)d_in[0];
  const int*   eidx = (const int*)d_in[1];
  const float* W    = (const float*)d_in[2];
  const float* b    = (const float*)d_in[3];
  float* out = (float*)d_out;

  const int* erow = eidx;            // sources
  const int* ecol = eidx + N_EDGES;  // destinations

  char* ws = (char*)d_ws;
  size_t off = 0;
  auto alloc = [&](size_t bytes) -> void* {
    void* p = ws + off;
    off = (off + bytes + 255) & ~(size_t)255;
    return p;
  };
  float* xw     = (float*)alloc((size_t)N_NODES * OUT_DIM * sizeof(float));  // 51.2MB
  short* WT     = (short*)alloc((size_t)OUT_DIM * IN_DIM * sizeof(short));   // 128KB
  float* dinv   = (float*)alloc((size_t)N_NODES * sizeof(float));
  int*   deg    = (int*)alloc((size_t)N_NODES * sizeof(int));
  int*   offs   = (int*)alloc((size_t)(N_NODES + 1) * sizeof(int));
  int*   cursor = (int*)alloc((size_t)N_NODES * sizeof(int));
  int*   bsum   = (int*)alloc((size_t)NSCAN_BLOCKS * sizeof(int));
  int*   bpre   = (int*)alloc((size_t)NSCAN_BLOCKS * sizeof(int));
  int*   brow   = (int*)alloc((size_t)N_EDGES * sizeof(int));                // 12.8MB
  int*   slot   = (int*)alloc((size_t)N_EDGES * sizeof(int));                // 12.8MB
  const bool two_pass = (off <= ws_size);

  hipMemsetAsync(deg, 0, (size_t)N_NODES * sizeof(int), stream);

  cast_WT<<<256, 256, 0, stream>>>(W, WT);

  if (two_pass) {
    count_slot<<<2048, 256, 0, stream>>>(ecol, deg, slot);
    block_sums<<<NSCAN_BLOCKS, 256, 0, stream>>>(deg, bsum);
    scan_bsums<<<1, 512, 0, stream>>>(bsum, bpre, offs);
    scan_final<<<NSCAN_BLOCKS, 256, 0, stream>>>(deg, bpre, offs, cursor, dinv);
    bucket_noatomic<<<2048, 256, 0, stream>>>(erow, ecol, slot, offs, brow);
  } else {
    count_only<<<2048, 256, 0, stream>>>(ecol, deg);
    block_sums<<<NSCAN_BLOCKS, 256, 0, stream>>>(deg, bsum);
    scan_bsums<<<1, 512, 0, stream>>>(bsum, bpre, offs);
    scan_final<<<NSCAN_BLOCKS, 256, 0, stream>>>(deg, bpre, offs, cursor, dinv);
    bucket_atomic<<<2048, 256, 0, stream>>>(erow, ecol, cursor, brow);
  }

  gemm_mfma<<<(N_NODES + 63) / 64, 256, 0, stream>>>(x, WT, xw);
  gather_out<<<(N_NODES + 3) / 4, 256, 0, stream>>>(xw, dinv, offs, brow, b, out);
}

// Round 4
// 472.027 us; speedup vs baseline: 2.2903x; 1.2070x over previous
//
#include <hip/hip_runtime.h>

using short8 = __attribute__((ext_vector_type(8))) short;
using f32x4  = __attribute__((ext_vector_type(4))) float;

static constexpr int N_NODES = 100000;
static constexpr int N_EDGES = 3200000;
static constexpr int IN_DIM  = 512;
static constexpr int OUT_DIM = 128;
static constexpr int NSCAN_BLOCKS = (N_NODES + 255) / 256;  // 391

__device__ __forceinline__ short f2bf(float f) {
  unsigned u = __builtin_bit_cast(unsigned, f);
  u = (u + 0x7FFFu + ((u >> 16) & 1u)) >> 16;  // RNE
  return (short)u;
}

// ---------------- W [512][128] f32  ->  WT [128][512] bf16 ----------------
__global__ __launch_bounds__(256) void cast_WT(const float* __restrict__ W,
                                               short* __restrict__ WT) {
  const int idx = blockIdx.x * 256 + threadIdx.x;  // 65536 total
  const int c = idx >> 9, k = idx & 511;
  WT[(size_t)c * 512 + k] = f2bf(W[(size_t)k * 128 + c]);
}

// ---------------- MFMA GEMM: xw = x @ W (bf16 in, bf16 out) ----------------
__global__ __launch_bounds__(256) void gemm_mfma(const float* __restrict__ x,
                                                 const short* __restrict__ WT,
                                                 unsigned short* __restrict__ xwb) {
  __shared__ short As[64 * 512];  // 64KB, row-major, byte^((row&7)<<4) swizzle
  const int tid  = threadIdx.x;
  const int row0 = blockIdx.x * 64;

#pragma unroll
  for (int it = 0; it < 16; ++it) {
    const int flat = it * 2048 + tid * 8;
    const int r = flat >> 9;
    const int k = flat & 511;
    short8 sv = {};
    if (row0 + r < N_NODES) {
      const float* s = &x[(size_t)(row0 + r) * IN_DIM + k];
      const float4 f0 = *reinterpret_cast<const float4*>(s);
      const float4 f1 = *reinterpret_cast<const float4*>(s + 4);
      sv[0] = f2bf(f0.x); sv[1] = f2bf(f0.y); sv[2] = f2bf(f0.z); sv[3] = f2bf(f0.w);
      sv[4] = f2bf(f1.x); sv[5] = f2bf(f1.y); sv[6] = f2bf(f1.z); sv[7] = f2bf(f1.w);
    }
    const int byte = (k * 2) ^ ((r & 7) << 4);
    *reinterpret_cast<short8*>(reinterpret_cast<char*>(As) + r * 1024 + byte) = sv;
  }
  __syncthreads();

  const int l  = tid & 63;
  const int w  = tid >> 6;
  const int wr = w >> 1, wc = w & 1;
  const int lr = l & 15;
  const int lk = l >> 4;

  const int arow0 = wr * 32 + lr;
  const int arow1 = arow0 + 16;
  const char* a0base = reinterpret_cast<const char*>(As) + arow0 * 1024;
  const char* a1base = reinterpret_cast<const char*>(As) + arow1 * 1024;
  const int rx0 = (arow0 & 7) << 4;
  const int rx1 = (arow1 & 7) << 4;

  const short8* b0 = reinterpret_cast<const short8*>(WT + (size_t)(wc * 64 +  0 + lr) * 512) + lk;
  const short8* b1 = reinterpret_cast<const short8*>(WT + (size_t)(wc * 64 + 16 + lr) * 512) + lk;
  const short8* b2 = reinterpret_cast<const short8*>(WT + (size_t)(wc * 64 + 32 + lr) * 512) + lk;
  const short8* b3 = reinterpret_cast<const short8*>(WT + (size_t)(wc * 64 + 48 + lr) * 512) + lk;

  f32x4 acc[2][4] = {};

#pragma unroll 4
  for (int ks = 0; ks < 16; ++ks) {
    const int kb = ks * 64 + lk * 16;
    const short8 a0 = *reinterpret_cast<const short8*>(a0base + (kb ^ rx0));
    const short8 a1 = *reinterpret_cast<const short8*>(a1base + (kb ^ rx1));
    const short8 bb0 = b0[ks * 4];
    const short8 bb1 = b1[ks * 4];
    const short8 bb2 = b2[ks * 4];
    const short8 bb3 = b3[ks * 4];
    acc[0][0] = __builtin_amdgcn_mfma_f32_16x16x32_bf16(a0, bb0, acc[0][0], 0, 0, 0);
    acc[0][1] = __builtin_amdgcn_mfma_f32_16x16x32_bf16(a0, bb1, acc[0][1], 0, 0, 0);
    acc[0][2] = __builtin_amdgcn_mfma_f32_16x16x32_bf16(a0, bb2, acc[0][2], 0, 0, 0);
    acc[0][3] = __builtin_amdgcn_mfma_f32_16x16x32_bf16(a0, bb3, acc[0][3], 0, 0, 0);
    acc[1][0] = __builtin_amdgcn_mfma_f32_16x16x32_bf16(a1, bb0, acc[1][0], 0, 0, 0);
    acc[1][1] = __builtin_amdgcn_mfma_f32_16x16x32_bf16(a1, bb1, acc[1][1], 0, 0, 0);
    acc[1][2] = __builtin_amdgcn_mfma_f32_16x16x32_bf16(a1, bb2, acc[1][2], 0, 0, 0);
    acc[1][3] = __builtin_amdgcn_mfma_f32_16x16x32_bf16(a1, bb3, acc[1][3], 0, 0, 0);
  }

#pragma unroll
  for (int m = 0; m < 2; ++m) {
    const int rbase = row0 + wr * 32 + m * 16 + (l >> 4) * 4;
#pragma unroll
    for (int j = 0; j < 4; ++j) {
      const int row = rbase + j;
      if (row < N_NODES) {
        unsigned short* o = &xwb[(size_t)row * OUT_DIM + wc * 64 + lr];
        o[0]  = (unsigned short)f2bf(acc[m][0][j]);
        o[16] = (unsigned short)f2bf(acc[m][1][j]);
        o[32] = (unsigned short)f2bf(acc[m][2][j]);
        o[48] = (unsigned short)f2bf(acc[m][3][j]);
      }
    }
  }
}

// ---------------- histogram (4-way sub-counters) + slot assignment ----------
__global__ void count_slot(const int* __restrict__ col, int* __restrict__ cnt,
                           int* __restrict__ slot) {
  int e = blockIdx.x * blockDim.x + threadIdx.x;
  const int stride = gridDim.x * blockDim.x;
  for (; e < N_EDGES; e += stride) {
    const int sub = e & 3;
    slot[e] = atomicAdd(&cnt[sub * N_NODES + col[e]], 1);
  }
}

// ---------------- 3-phase device-wide exclusive scan over deg ----------------
__global__ __launch_bounds__(256) void block_sums(const int* __restrict__ cnt,
                                                  int* __restrict__ bsum) {
  const int i = blockIdx.x * 256 + threadIdx.x;
  int v = 0;
  if (i < N_NODES)
    v = cnt[i] + cnt[N_NODES + i] + cnt[2 * N_NODES + i] + cnt[3 * N_NODES + i];
#pragma unroll
  for (int d = 1; d < 64; d <<= 1) v += __shfl_xor(v, d);
  __shared__ int part[4];
  if ((threadIdx.x & 63) == 0) part[threadIdx.x >> 6] = v;
  __syncthreads();
  if (threadIdx.x == 0) bsum[blockIdx.x] = part[0] + part[1] + part[2] + part[3];
}

__global__ __launch_bounds__(512) void scan_bsums(int* __restrict__ bsum,
                                                  int* __restrict__ bpre,
                                                  int* __restrict__ offs) {
  __shared__ int sh[512];
  const int tid = threadIdx.x;
  int v = (tid < NSCAN_BLOCKS) ? bsum[tid] : 0;
  sh[tid] = v;
  __syncthreads();
  for (int d = 1; d < 512; d <<= 1) {
    int t = (tid >= d) ? sh[tid - d] : 0;
    __syncthreads();
    sh[tid] += t;
    __syncthreads();
  }
  if (tid < NSCAN_BLOCKS) bpre[tid] = sh[tid] - v;  // exclusive
  if (tid == NSCAN_BLOCKS - 1) offs[N_NODES] = sh[tid];
}

__global__ __launch_bounds__(256) void scan_final(const int* __restrict__ cnt,
                                                  const int* __restrict__ bpre,
                                                  int* __restrict__ offs,
                                                  int4* __restrict__ qbase,
                                                  float* __restrict__ dinv) {
  __shared__ int sh[256];
  const int tid = threadIdx.x;
  const int i = blockIdx.x * 256 + tid;
  int c0 = 0, c1 = 0, c2 = 0, c3 = 0;
  if (i < N_NODES) {
    c0 = cnt[i];
    c1 = cnt[N_NODES + i];
    c2 = cnt[2 * N_NODES + i];
    c3 = cnt[3 * N_NODES + i];
  }
  const int d0 = c0 + c1 + c2 + c3;
  sh[tid] = d0;
  __syncthreads();
  for (int d = 1; d < 256; d <<= 1) {
    int t = (tid >= d) ? sh[tid - d] : 0;
    __syncthreads();
    sh[tid] += t;
    __syncthreads();
  }
  if (i < N_NODES) {
    const int off = bpre[blockIdx.x] + sh[tid] - d0;  // exclusive prefix
    offs[i] = off;
    qbase[i] = make_int4(off, off + c0, off + c0 + c1, off + c0 + c1 + c2);
    dinv[i] = rsqrtf((float)d0 + 1.0f);
  }
}

// ---------------- bucket: atomic-free permutation write ----------------
__global__ void bucket_noatomic(const int* __restrict__ row, const int* __restrict__ col,
                                const int* __restrict__ slot,
                                const int4* __restrict__ qbase,
                                int* __restrict__ brow) {
  int e = blockIdx.x * blockDim.x + threadIdx.x;
  const int stride = gridDim.x * blockDim.x;
  for (; e < N_EDGES; e += stride) {
    const int sub = e & 3;
    const int4 q = qbase[col[e]];
    const int base = (sub == 0) ? q.x : (sub == 1) ? q.y : (sub == 2) ? q.z : q.w;
    brow[base + slot[e]] = row[e];
  }
}

// ---------------- gather: one wave per destination node (bf16 xw) ----------
__global__ __launch_bounds__(256) void gather_out(const unsigned short* __restrict__ xwb,
                                                  const float* __restrict__ dinv,
                                                  const int* __restrict__ offs,
                                                  const int* __restrict__ brow,
                                                  const float* __restrict__ bias,
                                                  float* __restrict__ out) {
  const int lane = threadIdx.x & 63;
  const int node = blockIdx.x * (blockDim.x >> 6) + (threadIdx.x >> 6);
  if (node >= N_NODES) return;
  const float di = dinv[node];
  const int c0 = lane * 2;

  auto ld2 = [&](int r) -> float2 {
    const unsigned v = *reinterpret_cast<const unsigned*>(&xwb[(size_t)r * OUT_DIM + c0]);
    float2 f;
    f.x = __builtin_bit_cast(float, v << 16);
    f.y = __builtin_bit_cast(float, v & 0xFFFF0000u);
    return f;
  };

  float2 acc;
  {
    const float2 v = ld2(node);
    const float s = di * di;
    acc.x = v.x * s;
    acc.y = v.y * s;
  }

  int e = offs[node];
  const int e1 = offs[node + 1];
  for (; e + 4 <= e1; e += 4) {
    const int r0 = brow[e], r1 = brow[e + 1], r2 = brow[e + 2], r3 = brow[e + 3];
    const float n0 = dinv[r0] * di;
    const float n1 = dinv[r1] * di;
    const float n2 = dinv[r2] * di;
    const float n3 = dinv[r3] * di;
    const float2 v0 = ld2(r0), v1 = ld2(r1), v2 = ld2(r2), v3 = ld2(r3);
    acc.x += v0.x * n0 + v1.x * n1 + v2.x * n2 + v3.x * n3;
    acc.y += v0.y * n0 + v1.y * n1 + v2.y * n2 + v3.y * n3;
  }
  for (; e < e1; ++e) {
    const int r = brow[e];
    const float nr = dinv[r] * di;
    const float2 v = ld2(r);
    acc.x += v.x * nr;
    acc.y += v.y * nr;
  }

  const float2 bb = *reinterpret_cast<const float2*>(&bias[c0]);
  float2 o;
  o.x = acc.x + bb.x;
  o.y = acc.y + bb.y;
  *reinterpret_cast<float2*>(&out[(size_t)node * OUT_DIM + c0]) = o;
}

extern "C" void kernel_launch(void* const* d_in, const int* in_sizes, int n_in,
                              void* d_out, int out_size, void* d_ws, size_t ws_size,
                              hipStream_t stream) {
  const float* x    = (const float*)d_in[0];
  const int*   eidx = (const int*)d_in[1];
  const float* W    = (const float*)d_in[2];
  const float* b    = (const float*)d_in[3];
  float* out = (float*)d_out;

  const int* erow = eidx;            // sources
  const int* ecol = eidx + N_EDGES;  // destinations

  char* ws = (char*)d_ws;
  size_t off = 0;
  auto alloc = [&](size_t bytes) -> void* {
    void* p = ws + off;
    off = (off + bytes + 255) & ~(size_t)255;
    return p;
  };
  unsigned short* xwb = (unsigned short*)alloc((size_t)N_NODES * OUT_DIM * sizeof(short)); // 25.6MB
  short* WT     = (short*)alloc((size_t)OUT_DIM * IN_DIM * sizeof(short));   // 128KB
  float* dinv   = (float*)alloc((size_t)N_NODES * sizeof(float));
  int*   cnt    = (int*)alloc((size_t)4 * N_NODES * sizeof(int));            // 1.6MB
  int*   offs   = (int*)alloc((size_t)(N_NODES + 1) * sizeof(int));
  int4*  qbase  = (int4*)alloc((size_t)N_NODES * sizeof(int4));              // 1.6MB
  int*   bsum   = (int*)alloc((size_t)NSCAN_BLOCKS * sizeof(int));
  int*   bpre   = (int*)alloc((size_t)NSCAN_BLOCKS * sizeof(int));
  int*   brow   = (int*)alloc((size_t)N_EDGES * sizeof(int));                // 12.8MB
  int*   slot   = (int*)alloc((size_t)N_EDGES * sizeof(int));                // 12.8MB

  hipMemsetAsync(cnt, 0, (size_t)4 * N_NODES * sizeof(int), stream);

  cast_WT<<<256, 256, 0, stream>>>(W, WT);

  count_slot<<<2048, 256, 0, stream>>>(ecol, cnt, slot);
  block_sums<<<NSCAN_BLOCKS, 256, 0, stream>>>(cnt, bsum);
  scan_bsums<<<1, 512, 0, stream>>>(bsum, bpre, offs);
  scan_final<<<NSCAN_BLOCKS, 256, 0, stream>>>(cnt, bpre, offs, qbase, dinv);
  bucket_noatomic<<<2048, 256, 0, stream>>>(erow, ecol, slot, qbase, brow);

  gemm_mfma<<<(N_NODES + 63) / 64, 256, 0, stream>>>(x, WT, xwb);
  gather_out<<<(N_NODES + 3) / 4, 256, 0, stream>>>(xwb, dinv, offs, brow, b, out);
}

// Round 5
// 336.418 us; speedup vs baseline: 3.2134x; 1.4031x over previous
//
#include <hip/hip_runtime.h>

using short8 = __attribute__((ext_vector_type(8))) short;
using f32x4  = __attribute__((ext_vector_type(4))) float;

static constexpr int N_NODES = 100000;
static constexpr int N_EDGES = 3200000;
static constexpr int IN_DIM  = 512;
static constexpr int OUT_DIM = 128;
static constexpr int NBINS   = (N_NODES + 255) / 256;  // 391 bins of 256 nodes
static constexpr int NB      = 1024;                   // binning blocks
static constexpr int CHUNK   = N_EDGES / NB;           // 3125 edges/block (exact)

__device__ __forceinline__ short f2bf(float f) {
  unsigned u = __builtin_bit_cast(unsigned, f);
  u = (u + 0x7FFFu + ((u >> 16) & 1u)) >> 16;  // RNE
  return (short)u;
}

// ---------------- W [512][128] f32  ->  WT [128][512] bf16 ----------------
__global__ __launch_bounds__(256) void cast_WT(const float* __restrict__ W,
                                               short* __restrict__ WT) {
  const int idx = blockIdx.x * 256 + threadIdx.x;  // 65536 total
  const int c = idx >> 9, k = idx & 511;
  WT[(size_t)c * 512 + k] = f2bf(W[(size_t)k * 128 + c]);
}

// ---------------- MFMA GEMM: xw = x @ W (bf16 in, bf16 out) ----------------
__global__ __launch_bounds__(256) void gemm_mfma(const float* __restrict__ x,
                                                 const short* __restrict__ WT,
                                                 unsigned short* __restrict__ xwb) {
  __shared__ short As[64 * 512];  // 64KB, row-major, byte^((row&7)<<4) swizzle
  const int tid  = threadIdx.x;
  const int row0 = blockIdx.x * 64;

#pragma unroll
  for (int it = 0; it < 16; ++it) {
    const int flat = it * 2048 + tid * 8;
    const int r = flat >> 9;
    const int k = flat & 511;
    short8 sv = {};
    if (row0 + r < N_NODES) {
      const float* s = &x[(size_t)(row0 + r) * IN_DIM + k];
      const float4 f0 = *reinterpret_cast<const float4*>(s);
      const float4 f1 = *reinterpret_cast<const float4*>(s + 4);
      sv[0] = f2bf(f0.x); sv[1] = f2bf(f0.y); sv[2] = f2bf(f0.z); sv[3] = f2bf(f0.w);
      sv[4] = f2bf(f1.x); sv[5] = f2bf(f1.y); sv[6] = f2bf(f1.z); sv[7] = f2bf(f1.w);
    }
    const int byte = (k * 2) ^ ((r & 7) << 4);
    *reinterpret_cast<short8*>(reinterpret_cast<char*>(As) + r * 1024 + byte) = sv;
  }
  __syncthreads();

  const int l  = tid & 63;
  const int w  = tid >> 6;
  const int wr = w >> 1, wc = w & 1;
  const int lr = l & 15;
  const int lk = l >> 4;

  const int arow0 = wr * 32 + lr;
  const int arow1 = arow0 + 16;
  const char* a0base = reinterpret_cast<const char*>(As) + arow0 * 1024;
  const char* a1base = reinterpret_cast<const char*>(As) + arow1 * 1024;
  const int rx0 = (arow0 & 7) << 4;
  const int rx1 = (arow1 & 7) << 4;

  const short8* b0 = reinterpret_cast<const short8*>(WT + (size_t)(wc * 64 +  0 + lr) * 512) + lk;
  const short8* b1 = reinterpret_cast<const short8*>(WT + (size_t)(wc * 64 + 16 + lr) * 512) + lk;
  const short8* b2 = reinterpret_cast<const short8*>(WT + (size_t)(wc * 64 + 32 + lr) * 512) + lk;
  const short8* b3 = reinterpret_cast<const short8*>(WT + (size_t)(wc * 64 + 48 + lr) * 512) + lk;

  f32x4 acc[2][4] = {};

#pragma unroll 4
  for (int ks = 0; ks < 16; ++ks) {
    const int kb = ks * 64 + lk * 16;
    const short8 a0 = *reinterpret_cast<const short8*>(a0base + (kb ^ rx0));
    const short8 a1 = *reinterpret_cast<const short8*>(a1base + (kb ^ rx1));
    const short8 bb0 = b0[ks * 4];
    const short8 bb1 = b1[ks * 4];
    const short8 bb2 = b2[ks * 4];
    const short8 bb3 = b3[ks * 4];
    acc[0][0] = __builtin_amdgcn_mfma_f32_16x16x32_bf16(a0, bb0, acc[0][0], 0, 0, 0);
    acc[0][1] = __builtin_amdgcn_mfma_f32_16x16x32_bf16(a0, bb1, acc[0][1], 0, 0, 0);
    acc[0][2] = __builtin_amdgcn_mfma_f32_16x16x32_bf16(a0, bb2, acc[0][2], 0, 0, 0);
    acc[0][3] = __builtin_amdgcn_mfma_f32_16x16x32_bf16(a0, bb3, acc[0][3], 0, 0, 0);
    acc[1][0] = __builtin_amdgcn_mfma_f32_16x16x32_bf16(a1, bb0, acc[1][0], 0, 0, 0);
    acc[1][1] = __builtin_amdgcn_mfma_f32_16x16x32_bf16(a1, bb1, acc[1][1], 0, 0, 0);
    acc[1][2] = __builtin_amdgcn_mfma_f32_16x16x32_bf16(a1, bb2, acc[1][2], 0, 0, 0);
    acc[1][3] = __builtin_amdgcn_mfma_f32_16x16x32_bf16(a1, bb3, acc[1][3], 0, 0, 0);
  }

#pragma unroll
  for (int m = 0; m < 2; ++m) {
    const int rbase = row0 + wr * 32 + m * 16 + (l >> 4) * 4;
#pragma unroll
    for (int j = 0; j < 4; ++j) {
      const int row = rbase + j;
      if (row < N_NODES) {
        unsigned short* o = &xwb[(size_t)row * OUT_DIM + wc * 64 + lr];
        o[0]  = (unsigned short)f2bf(acc[m][0][j]);
        o[16] = (unsigned short)f2bf(acc[m][1][j]);
        o[32] = (unsigned short)f2bf(acc[m][2][j]);
        o[48] = (unsigned short)f2bf(acc[m][3][j]);
      }
    }
  }
}

// ========== atomic-free edge grouping: 2-level binning, LDS-only atomics ====

// A1: per-block LDS histogram of bin = col>>8
__global__ __launch_bounds__(256) void bin_count(const int* __restrict__ ecol,
                                                 int* __restrict__ blkhist) {
  __shared__ int hist[NBINS];
  const int blk = blockIdx.x, tid = threadIdx.x;
  for (int i = tid; i < NBINS; i += 256) hist[i] = 0;
  __syncthreads();
  const int e0 = blk * CHUNK, e1 = e0 + CHUNK;
  for (int e = e0 + tid; e < e1; e += 256) atomicAdd(&hist[ecol[e] >> 8], 1);
  __syncthreads();
  for (int i = tid; i < NBINS; i += 256) blkhist[(size_t)blk * NBINS + i] = hist[i];
}

// A2a: per-bin exclusive scan over the NB block partials (in place)
__global__ __launch_bounds__(1024) void scan_blkhist(int* __restrict__ blkhist,
                                                     int* __restrict__ bintot) {
  __shared__ int sh[NB];
  const int bin = blockIdx.x, t = threadIdx.x;
  const int v = blkhist[(size_t)t * NBINS + bin];
  sh[t] = v;
  __syncthreads();
  for (int d = 1; d < NB; d <<= 1) {
    const int tv = (t >= d) ? sh[t - d] : 0;
    __syncthreads();
    sh[t] += tv;
    __syncthreads();
  }
  blkhist[(size_t)t * NBINS + bin] = sh[t] - v;  // exclusive prefix over blocks
  if (t == NB - 1) bintot[bin] = sh[t];
}

// A2b: exclusive scan over bin totals
__global__ __launch_bounds__(512) void scan_bins(const int* __restrict__ bintot,
                                                 int* __restrict__ binbase) {
  __shared__ int sh[512];
  const int t = threadIdx.x;
  const int v = (t < NBINS) ? bintot[t] : 0;
  sh[t] = v;
  __syncthreads();
  for (int d = 1; d < 512; d <<= 1) {
    const int tv = (t >= d) ? sh[t - d] : 0;
    __syncthreads();
    sh[t] += tv;
    __syncthreads();
  }
  if (t < NBINS) binbase[t] = sh[t] - v;
  if (t == NBINS - 1) binbase[NBINS] = sh[t];
}

// A3: scatter (row,col) into bin-segmented benc using LDS cursors
__global__ __launch_bounds__(256) void bin_scatter(const int* __restrict__ erow,
                                                   const int* __restrict__ ecol,
                                                   const int* __restrict__ blkhist,
                                                   const int* __restrict__ binbase,
                                                   int2* __restrict__ benc) {
  __shared__ int cur[NBINS];
  const int blk = blockIdx.x, tid = threadIdx.x;
  for (int i = tid; i < NBINS; i += 256)
    cur[i] = binbase[i] + blkhist[(size_t)blk * NBINS + i];
  __syncthreads();
  const int e0 = blk * CHUNK, e1 = e0 + CHUNK;
  for (int e = e0 + tid; e < e1; e += 256) {
    const int c = ecol[e];
    const int r = erow[e];
    const int p = atomicAdd(&cur[c >> 8], 1);
    benc[p] = make_int2(r, c);
  }
}

// B: per-bin CSR build — offs, dinv, brow (one block per 256-node bin)
__global__ __launch_bounds__(256) void bin_build(const int2* __restrict__ benc,
                                                 const int* __restrict__ binbase,
                                                 int* __restrict__ brow,
                                                 int* __restrict__ offs,
                                                 float* __restrict__ dinv) {
  __shared__ int hist[256];
  __shared__ int sh[256];
  __shared__ int cur[256];
  const int b = blockIdx.x, tid = threadIdx.x;
  const int n0 = b << 8;
  const int e0 = binbase[b], e1 = binbase[b + 1];
  hist[tid] = 0;
  __syncthreads();
  for (int e = e0 + tid; e < e1; e += 256) atomicAdd(&hist[benc[e].y - n0], 1);
  __syncthreads();
  const int d0 = hist[tid];
  sh[tid] = d0;
  __syncthreads();
  for (int d = 1; d < 256; d <<= 1) {
    const int tv = (tid >= d) ? sh[tid - d] : 0;
    __syncthreads();
    sh[tid] += tv;
    __syncthreads();
  }
  const int myoff = e0 + sh[tid] - d0;  // global CSR offset for node n0+tid
  cur[tid] = myoff;
  const int node = n0 + tid;
  if (node < N_NODES) {
    offs[node] = myoff;
    dinv[node] = rsqrtf((float)d0 + 1.0f);
  }
  if (b == NBINS - 1 && tid == 255) offs[N_NODES] = e1;
  __syncthreads();
  for (int e = e0 + tid; e < e1; e += 256) {
    const int2 rc = benc[e];
    const int p = atomicAdd(&cur[rc.y - n0], 1);
    brow[p] = rc.x;
  }
}

// ---------------- gather: one wave per destination node (bf16 xw) ----------
__global__ __launch_bounds__(256) void gather_out(const unsigned short* __restrict__ xwb,
                                                  const float* __restrict__ dinv,
                                                  const int* __restrict__ offs,
                                                  const int* __restrict__ brow,
                                                  const float* __restrict__ bias,
                                                  float* __restrict__ out) {
  const int lane = threadIdx.x & 63;
  const int node = blockIdx.x * (blockDim.x >> 6) + (threadIdx.x >> 6);
  if (node >= N_NODES) return;
  const float di = dinv[node];
  const int c0 = lane * 2;

  auto ld2 = [&](int r) -> float2 {
    const unsigned v = *reinterpret_cast<const unsigned*>(&xwb[(size_t)r * OUT_DIM + c0]);
    float2 f;
    f.x = __builtin_bit_cast(float, v << 16);
    f.y = __builtin_bit_cast(float, v & 0xFFFF0000u);
    return f;
  };

  float2 acc;
  {
    const float2 v = ld2(node);
    const float s = di * di;
    acc.x = v.x * s;
    acc.y = v.y * s;
  }

  int e = offs[node];
  const int e1 = offs[node + 1];
  for (; e + 4 <= e1; e += 4) {
    const int r0 = brow[e], r1 = brow[e + 1], r2 = brow[e + 2], r3 = brow[e + 3];
    const float n0 = dinv[r0] * di;
    const float n1 = dinv[r1] * di;
    const float n2 = dinv[r2] * di;
    const float n3 = dinv[r3] * di;
    const float2 v0 = ld2(r0), v1 = ld2(r1), v2 = ld2(r2), v3 = ld2(r3);
    acc.x += v0.x * n0 + v1.x * n1 + v2.x * n2 + v3.x * n3;
    acc.y += v0.y * n0 + v1.y * n1 + v2.y * n2 + v3.y * n3;
  }
  for (; e < e1; ++e) {
    const int r = brow[e];
    const float nr = dinv[r] * di;
    const float2 v = ld2(r);
    acc.x += v.x * nr;
    acc.y += v.y * nr;
  }

  const float2 bb = *reinterpret_cast<const float2*>(&bias[c0]);
  float2 o;
  o.x = acc.x + bb.x;
  o.y = acc.y + bb.y;
  *reinterpret_cast<float2*>(&out[(size_t)node * OUT_DIM + c0]) = o;
}

extern "C" void kernel_launch(void* const* d_in, const int* in_sizes, int n_in,
                              void* d_out, int out_size, void* d_ws, size_t ws_size,
                              hipStream_t stream) {
  const float* x    = (const float*)d_in[0];
  const int*   eidx = (const int*)d_in[1];
  const float* W    = (const float*)d_in[2];
  const float* b    = (const float*)d_in[3];
  float* out = (float*)d_out;

  const int* erow = eidx;            // sources
  const int* ecol = eidx + N_EDGES;  // destinations

  char* ws = (char*)d_ws;
  size_t off = 0;
  auto alloc = [&](size_t bytes) -> void* {
    void* p = ws + off;
    off = (off + bytes + 255) & ~(size_t)255;
    return p;
  };
  unsigned short* xwb = (unsigned short*)alloc((size_t)N_NODES * OUT_DIM * sizeof(short)); // 25.6MB
  short* WT      = (short*)alloc((size_t)OUT_DIM * IN_DIM * sizeof(short));    // 128KB
  float* dinv    = (float*)alloc((size_t)N_NODES * sizeof(float));             // 400KB
  int*   offs    = (int*)alloc((size_t)(N_NODES + 1) * sizeof(int));           // 400KB
  int*   blkhist = (int*)alloc((size_t)NB * NBINS * sizeof(int));              // 1.6MB
  int*   bintot  = (int*)alloc((size_t)NBINS * sizeof(int));
  int*   binbase = (int*)alloc((size_t)(NBINS + 1) * sizeof(int));
  int*   brow    = (int*)alloc((size_t)N_EDGES * sizeof(int));                 // 12.8MB
  int2*  benc    = (int2*)alloc((size_t)N_EDGES * sizeof(int2));               // 25.6MB

  cast_WT<<<256, 256, 0, stream>>>(W, WT);

  bin_count<<<NB, 256, 0, stream>>>(ecol, blkhist);
  scan_blkhist<<<NBINS, NB, 0, stream>>>(blkhist, bintot);
  scan_bins<<<1, 512, 0, stream>>>(bintot, binbase);
  bin_scatter<<<NB, 256, 0, stream>>>(erow, ecol, blkhist, binbase, benc);
  bin_build<<<NBINS, 256, 0, stream>>>(benc, binbase, brow, offs, dinv);

  gemm_mfma<<<(N_NODES + 63) / 64, 256, 0, stream>>>(x, WT, xwb);
  gather_out<<<(N_NODES + 3) / 4, 256, 0, stream>>>(xwb, dinv, offs, brow, b, out);
}

// Round 6
// 321.346 us; speedup vs baseline: 3.3642x; 1.0469x over previous
//
#include <hip/hip_runtime.h>

using short8 = __attribute__((ext_vector_type(8))) short;
using f32x4  = __attribute__((ext_vector_type(4))) float;

static constexpr int N_NODES = 100000;
static constexpr int N_EDGES = 3200000;
static constexpr int IN_DIM  = 512;
static constexpr int OUT_DIM = 128;
static constexpr int NBINS   = (N_NODES + 255) / 256;  // 391 bins of 256 nodes
static constexpr int NB      = 1024;                   // binning blocks
static constexpr int CHUNK   = N_EDGES / NB;           // 3125 edges/block (exact)

__device__ __forceinline__ short f2bf(float f) {
  unsigned u = __builtin_bit_cast(unsigned, f);
  u = (u + 0x7FFFu + ((u >> 16) & 1u)) >> 16;  // RNE
  return (short)u;
}

// ---------------- W [512][128] f32  ->  WT [128][512] bf16 ----------------
__global__ __launch_bounds__(256) void cast_WT(const float* __restrict__ W,
                                               short* __restrict__ WT) {
  const int idx = blockIdx.x * 256 + threadIdx.x;  // 65536 total
  const int c = idx >> 9, k = idx & 511;
  WT[(size_t)c * 512 + k] = f2bf(W[(size_t)k * 128 + c]);
}

// ---------------- MFMA GEMM: xw = x @ W (bf16 in, bf16 out) ----------------
// BM=64, BK=128, double-buffered 2x16KB LDS -> 4 blocks/CU.
// Per kb-iter: issue next global loads -> 32 MFMA/wave on cur buf ->
// cast+ds_write next buf -> barrier.  (T14 issue-early/write-late)
__global__ __launch_bounds__(256) void gemm_mfma(const float* __restrict__ x,
                                                 const short* __restrict__ WT,
                                                 unsigned short* __restrict__ xwb) {
  __shared__ short As[2][64 * 128];  // 2 x 16KB, row=256B, byte^((row&7)<<4)
  const int tid  = threadIdx.x;
  const int row0 = blockIdx.x * 64;

  float4 pf[8];

  auto issue_loads = [&](int kb) {
#pragma unroll
    for (int c = 0; c < 4; ++c) {
      const int flat = c * 2048 + tid * 8;  // float idx in 64x128 tile
      const int r = flat >> 7;
      const int k = flat & 127;
      const int row = row0 + r;
      if (row < N_NODES) {
        const float* s = &x[(size_t)row * IN_DIM + kb + k];
        pf[c * 2]     = *reinterpret_cast<const float4*>(s);
        pf[c * 2 + 1] = *reinterpret_cast<const float4*>(s + 4);
      } else {
        pf[c * 2]     = make_float4(0.f, 0.f, 0.f, 0.f);
        pf[c * 2 + 1] = make_float4(0.f, 0.f, 0.f, 0.f);
      }
    }
  };

  auto write_lds = [&](int buf) {
#pragma unroll
    for (int c = 0; c < 4; ++c) {
      const int flat = c * 2048 + tid * 8;
      const int r = flat >> 7;
      const int k = flat & 127;
      const float4 f0 = pf[c * 2], f1 = pf[c * 2 + 1];
      short8 sv;
      sv[0] = f2bf(f0.x); sv[1] = f2bf(f0.y); sv[2] = f2bf(f0.z); sv[3] = f2bf(f0.w);
      sv[4] = f2bf(f1.x); sv[5] = f2bf(f1.y); sv[6] = f2bf(f1.z); sv[7] = f2bf(f1.w);
      const int byte = (k * 2) ^ ((r & 7) << 4);
      *reinterpret_cast<short8*>(reinterpret_cast<char*>(As[buf]) + r * 256 + byte) = sv;
    }
  };

  const int l  = tid & 63;
  const int w  = tid >> 6;
  const int wr = w >> 1, wc = w & 1;
  const int lr = l & 15;
  const int lk = l >> 4;

  const int arow0 = wr * 32 + lr;
  const int arow1 = arow0 + 16;
  const int ab0 = arow0 * 256, rx0 = (arow0 & 7) << 4;
  const int ab1 = arow1 * 256, rx1 = (arow1 & 7) << 4;

  const short* bB0 = WT + (size_t)(wc * 64 +  0 + lr) * 512 + lk * 8;
  const short* bB1 = WT + (size_t)(wc * 64 + 16 + lr) * 512 + lk * 8;
  const short* bB2 = WT + (size_t)(wc * 64 + 32 + lr) * 512 + lk * 8;
  const short* bB3 = WT + (size_t)(wc * 64 + 48 + lr) * 512 + lk * 8;

  f32x4 acc[2][4] = {};

  issue_loads(0);
  write_lds(0);
  __syncthreads();

#pragma unroll
  for (int kbidx = 0; kbidx < 4; ++kbidx) {
    const int cur = kbidx & 1;
    if (kbidx < 3) issue_loads((kbidx + 1) * 128);

    const char* base = reinterpret_cast<const char*>(As[cur]);
#pragma unroll
    for (int ks = 0; ks < 4; ++ks) {
      const int kbyte = ks * 64 + lk * 16;
      const short8 a0 = *reinterpret_cast<const short8*>(base + ab0 + (kbyte ^ rx0));
      const short8 a1 = *reinterpret_cast<const short8*>(base + ab1 + (kbyte ^ rx1));
      const int ko = kbidx * 128 + ks * 32;
      const short8 bb0 = *reinterpret_cast<const short8*>(bB0 + ko);
      const short8 bb1 = *reinterpret_cast<const short8*>(bB1 + ko);
      const short8 bb2 = *reinterpret_cast<const short8*>(bB2 + ko);
      const short8 bb3 = *reinterpret_cast<const short8*>(bB3 + ko);
      acc[0][0] = __builtin_amdgcn_mfma_f32_16x16x32_bf16(a0, bb0, acc[0][0], 0, 0, 0);
      acc[0][1] = __builtin_amdgcn_mfma_f32_16x16x32_bf16(a0, bb1, acc[0][1], 0, 0, 0);
      acc[0][2] = __builtin_amdgcn_mfma_f32_16x16x32_bf16(a0, bb2, acc[0][2], 0, 0, 0);
      acc[0][3] = __builtin_amdgcn_mfma_f32_16x16x32_bf16(a0, bb3, acc[0][3], 0, 0, 0);
      acc[1][0] = __builtin_amdgcn_mfma_f32_16x16x32_bf16(a1, bb0, acc[1][0], 0, 0, 0);
      acc[1][1] = __builtin_amdgcn_mfma_f32_16x16x32_bf16(a1, bb1, acc[1][1], 0, 0, 0);
      acc[1][2] = __builtin_amdgcn_mfma_f32_16x16x32_bf16(a1, bb2, acc[1][2], 0, 0, 0);
      acc[1][3] = __builtin_amdgcn_mfma_f32_16x16x32_bf16(a1, bb3, acc[1][3], 0, 0, 0);
    }

    if (kbidx < 3) {
      write_lds(cur ^ 1);
      __syncthreads();
    }
  }

#pragma unroll
  for (int m = 0; m < 2; ++m) {
    const int rbase = row0 + wr * 32 + m * 16 + (l >> 4) * 4;
#pragma unroll
    for (int j = 0; j < 4; ++j) {
      const int row = rbase + j;
      if (row < N_NODES) {
        unsigned short* o = &xwb[(size_t)row * OUT_DIM + wc * 64 + lr];
        o[0]  = (unsigned short)f2bf(acc[m][0][j]);
        o[16] = (unsigned short)f2bf(acc[m][1][j]);
        o[32] = (unsigned short)f2bf(acc[m][2][j]);
        o[48] = (unsigned short)f2bf(acc[m][3][j]);
      }
    }
  }
}

// ========== atomic-free edge grouping: 2-level binning, LDS-only atomics ====

// A1: per-block LDS histogram of bin = col>>8
__global__ __launch_bounds__(256) void bin_count(const int* __restrict__ ecol,
                                                 int* __restrict__ blkhist) {
  __shared__ int hist[NBINS];
  const int blk = blockIdx.x, tid = threadIdx.x;
  for (int i = tid; i < NBINS; i += 256) hist[i] = 0;
  __syncthreads();
  const int e0 = blk * CHUNK, e1 = e0 + CHUNK;
  for (int e = e0 + tid; e < e1; e += 256) atomicAdd(&hist[ecol[e] >> 8], 1);
  __syncthreads();
  for (int i = tid; i < NBINS; i += 256) blkhist[(size_t)blk * NBINS + i] = hist[i];
}

// A2a: per-bin exclusive scan over the NB block partials (in place)
__global__ __launch_bounds__(1024) void scan_blkhist(int* __restrict__ blkhist,
                                                     int* __restrict__ bintot) {
  __shared__ int sh[NB];
  const int bin = blockIdx.x, t = threadIdx.x;
  const int v = blkhist[(size_t)t * NBINS + bin];
  sh[t] = v;
  __syncthreads();
  for (int d = 1; d < NB; d <<= 1) {
    const int tv = (t >= d) ? sh[t - d] : 0;
    __syncthreads();
    sh[t] += tv;
    __syncthreads();
  }
  blkhist[(size_t)t * NBINS + bin] = sh[t] - v;  // exclusive prefix over blocks
  if (t == NB - 1) bintot[bin] = sh[t];
}

// A2b: exclusive scan over bin totals
__global__ __launch_bounds__(512) void scan_bins(const int* __restrict__ bintot,
                                                 int* __restrict__ binbase) {
  __shared__ int sh[512];
  const int t = threadIdx.x;
  const int v = (t < NBINS) ? bintot[t] : 0;
  sh[t] = v;
  __syncthreads();
  for (int d = 1; d < 512; d <<= 1) {
    const int tv = (t >= d) ? sh[t - d] : 0;
    __syncthreads();
    sh[t] += tv;
    __syncthreads();
  }
  if (t < NBINS) binbase[t] = sh[t] - v;
  if (t == NBINS - 1) binbase[NBINS] = sh[t];
}

// A3: scatter (row,col) into bin-segmented benc using LDS cursors
__global__ __launch_bounds__(256) void bin_scatter(const int* __restrict__ erow,
                                                   const int* __restrict__ ecol,
                                                   const int* __restrict__ blkhist,
                                                   const int* __restrict__ binbase,
                                                   int2* __restrict__ benc) {
  __shared__ int cur[NBINS];
  const int blk = blockIdx.x, tid = threadIdx.x;
  for (int i = tid; i < NBINS; i += 256)
    cur[i] = binbase[i] + blkhist[(size_t)blk * NBINS + i];
  __syncthreads();
  const int e0 = blk * CHUNK, e1 = e0 + CHUNK;
  for (int e = e0 + tid; e < e1; e += 256) {
    const int c = ecol[e];
    const int r = erow[e];
    const int p = atomicAdd(&cur[c >> 8], 1);
    benc[p] = make_int2(r, c);
  }
}

// B: per-bin CSR build — offs, dinv, brow (one block per 256-node bin)
__global__ __launch_bounds__(256) void bin_build(const int2* __restrict__ benc,
                                                 const int* __restrict__ binbase,
                                                 int* __restrict__ brow,
                                                 int* __restrict__ offs,
                                                 float* __restrict__ dinv) {
  __shared__ int hist[256];
  __shared__ int sh[256];
  __shared__ int cur[256];
  const int b = blockIdx.x, tid = threadIdx.x;
  const int n0 = b << 8;
  const int e0 = binbase[b], e1 = binbase[b + 1];
  hist[tid] = 0;
  __syncthreads();
  for (int e = e0 + tid; e < e1; e += 256) atomicAdd(&hist[benc[e].y - n0], 1);
  __syncthreads();
  const int d0 = hist[tid];
  sh[tid] = d0;
  __syncthreads();
  for (int d = 1; d < 256; d <<= 1) {
    const int tv = (tid >= d) ? sh[tid - d] : 0;
    __syncthreads();
    sh[tid] += tv;
    __syncthreads();
  }
  const int myoff = e0 + sh[tid] - d0;  // global CSR offset for node n0+tid
  cur[tid] = myoff;
  const int node = n0 + tid;
  if (node < N_NODES) {
    offs[node] = myoff;
    dinv[node] = rsqrtf((float)d0 + 1.0f);
  }
  if (b == NBINS - 1 && tid == 255) offs[N_NODES] = e1;
  __syncthreads();
  for (int e = e0 + tid; e < e1; e += 256) {
    const int2 rc = benc[e];
    const int p = atomicAdd(&cur[rc.y - n0], 1);
    brow[p] = rc.x;
  }
}

// ---------------- gather: one wave per destination node (bf16 xw) ----------
__global__ __launch_bounds__(256) void gather_out(const unsigned short* __restrict__ xwb,
                                                  const float* __restrict__ dinv,
                                                  const int* __restrict__ offs,
                                                  const int* __restrict__ brow,
                                                  const float* __restrict__ bias,
                                                  float* __restrict__ out) {
  const int lane = threadIdx.x & 63;
  const int node = blockIdx.x * (blockDim.x >> 6) + (threadIdx.x >> 6);
  if (node >= N_NODES) return;
  const float di = dinv[node];
  const int c0 = lane * 2;

  auto ld2 = [&](int r) -> float2 {
    const unsigned v = *reinterpret_cast<const unsigned*>(&xwb[(size_t)r * OUT_DIM + c0]);
    float2 f;
    f.x = __builtin_bit_cast(float, v << 16);
    f.y = __builtin_bit_cast(float, v & 0xFFFF0000u);
    return f;
  };

  float2 acc;
  {
    const float2 v = ld2(node);
    const float s = di * di;
    acc.x = v.x * s;
    acc.y = v.y * s;
  }

  int e = offs[node];
  const int e1 = offs[node + 1];
  for (; e + 4 <= e1; e += 4) {
    const int r0 = brow[e], r1 = brow[e + 1], r2 = brow[e + 2], r3 = brow[e + 3];
    const float n0 = dinv[r0] * di;
    const float n1 = dinv[r1] * di;
    const float n2 = dinv[r2] * di;
    const float n3 = dinv[r3] * di;
    const float2 v0 = ld2(r0), v1 = ld2(r1), v2 = ld2(r2), v3 = ld2(r3);
    acc.x += v0.x * n0 + v1.x * n1 + v2.x * n2 + v3.x * n3;
    acc.y += v0.y * n0 + v1.y * n1 + v2.y * n2 + v3.y * n3;
  }
  for (; e < e1; ++e) {
    const int r = brow[e];
    const float nr = dinv[r] * di;
    const float2 v = ld2(r);
    acc.x += v.x * nr;
    acc.y += v.y * nr;
  }

  const float2 bb = *reinterpret_cast<const float2*>(&bias[c0]);
  float2 o;
  o.x = acc.x + bb.x;
  o.y = acc.y + bb.y;
  *reinterpret_cast<float2*>(&out[(size_t)node * OUT_DIM + c0]) = o;
}

extern "C" void kernel_launch(void* const* d_in, const int* in_sizes, int n_in,
                              void* d_out, int out_size, void* d_ws, size_t ws_size,
                              hipStream_t stream) {
  const float* x    = (const float*)d_in[0];
  const int*   eidx = (const int*)d_in[1];
  const float* W    = (const float*)d_in[2];
  const float* b    = (const float*)d_in[3];
  float* out = (float*)d_out;

  const int* erow = eidx;            // sources
  const int* ecol = eidx + N_EDGES;  // destinations

  char* ws = (char*)d_ws;
  size_t off = 0;
  auto alloc = [&](size_t bytes) -> void* {
    void* p = ws + off;
    off = (off + bytes + 255) & ~(size_t)255;
    return p;
  };
  unsigned short* xwb = (unsigned short*)alloc((size_t)N_NODES * OUT_DIM * sizeof(short)); // 25.6MB
  short* WT      = (short*)alloc((size_t)OUT_DIM * IN_DIM * sizeof(short));    // 128KB
  float* dinv    = (float*)alloc((size_t)N_NODES * sizeof(float));             // 400KB
  int*   offs    = (int*)alloc((size_t)(N_NODES + 1) * sizeof(int));           // 400KB
  int*   blkhist = (int*)alloc((size_t)NB * NBINS * sizeof(int));              // 1.6MB
  int*   bintot  = (int*)alloc((size_t)NBINS * sizeof(int));
  int*   binbase = (int*)alloc((size_t)(NBINS + 1) * sizeof(int));
  int*   brow    = (int*)alloc((size_t)N_EDGES * sizeof(int));                 // 12.8MB
  int2*  benc    = (int2*)alloc((size_t)N_EDGES * sizeof(int2));               // 25.6MB

  cast_WT<<<256, 256, 0, stream>>>(W, WT);

  bin_count<<<NB, 256, 0, stream>>>(ecol, blkhist);
  scan_blkhist<<<NBINS, NB, 0, stream>>>(blkhist, bintot);
  scan_bins<<<1, 512, 0, stream>>>(bintot, binbase);
  bin_scatter<<<NB, 256, 0, stream>>>(erow, ecol, blkhist, binbase, benc);
  bin_build<<<NBINS, 256, 0, stream>>>(benc, binbase, brow, offs, dinv);

  gemm_mfma<<<(N_NODES + 63) / 64, 256, 0, stream>>>(x, WT, xwb);
  gather_out<<<(N_NODES + 3) / 4, 256, 0, stream>>>(xwb, dinv, offs, brow, b, out);
}

// Round 7
// 302.076 us; speedup vs baseline: 3.5788x; 1.0638x over previous
//
#include <hip/hip_runtime.h>

using short8 = __attribute__((ext_vector_type(8))) short;
using f32x4  = __attribute__((ext_vector_type(4))) float;

static constexpr int N_NODES = 100000;
static constexpr int N_EDGES = 3200000;
static constexpr int IN_DIM  = 512;
static constexpr int OUT_DIM = 128;
static constexpr int NBINS   = (N_NODES + 255) / 256;  // 391 bins of 256 nodes
static constexpr int NB      = 1024;                   // binning blocks
static constexpr int CHUNK   = N_EDGES / NB;           // 3125 edges/block (exact)

__device__ __forceinline__ short f2bf(float f) {
  unsigned u = __builtin_bit_cast(unsigned, f);
  u = (u + 0x7FFFu + ((u >> 16) & 1u)) >> 16;  // RNE
  return (short)u;
}

// ---------------- W [512][128] f32  ->  WT [128][512] bf16 ----------------
__global__ __launch_bounds__(256) void cast_WT(const float* __restrict__ W,
                                               short* __restrict__ WT) {
  const int idx = blockIdx.x * 256 + threadIdx.x;  // 65536 total
  const int c = idx >> 9, k = idx & 511;
  WT[(size_t)c * 512 + k] = f2bf(W[(size_t)k * 128 + c]);
}

// ---------------- MFMA GEMM: xwb = (x @ W) * dinv[row]  (bf16 out) --------
// BM=64, BK=128, double-buffered 2x16KB LDS.
__global__ __launch_bounds__(256) void gemm_mfma(const float* __restrict__ x,
                                                 const short* __restrict__ WT,
                                                 const float* __restrict__ dinv,
                                                 unsigned short* __restrict__ xwb) {
  __shared__ short As[2][64 * 128];  // 2 x 16KB, row=256B, byte^((row&7)<<4)
  const int tid  = threadIdx.x;
  const int row0 = blockIdx.x * 64;

  float4 pf[8];

  auto issue_loads = [&](int kb) {
#pragma unroll
    for (int c = 0; c < 4; ++c) {
      const int flat = c * 2048 + tid * 8;  // float idx in 64x128 tile
      const int r = flat >> 7;
      const int k = flat & 127;
      const int row = row0 + r;
      if (row < N_NODES) {
        const float* s = &x[(size_t)row * IN_DIM + kb + k];
        pf[c * 2]     = *reinterpret_cast<const float4*>(s);
        pf[c * 2 + 1] = *reinterpret_cast<const float4*>(s + 4);
      } else {
        pf[c * 2]     = make_float4(0.f, 0.f, 0.f, 0.f);
        pf[c * 2 + 1] = make_float4(0.f, 0.f, 0.f, 0.f);
      }
    }
  };

  auto write_lds = [&](int buf) {
#pragma unroll
    for (int c = 0; c < 4; ++c) {
      const int flat = c * 2048 + tid * 8;
      const int r = flat >> 7;
      const int k = flat & 127;
      const float4 f0 = pf[c * 2], f1 = pf[c * 2 + 1];
      short8 sv;
      sv[0] = f2bf(f0.x); sv[1] = f2bf(f0.y); sv[2] = f2bf(f0.z); sv[3] = f2bf(f0.w);
      sv[4] = f2bf(f1.x); sv[5] = f2bf(f1.y); sv[6] = f2bf(f1.z); sv[7] = f2bf(f1.w);
      const int byte = (k * 2) ^ ((r & 7) << 4);
      *reinterpret_cast<short8*>(reinterpret_cast<char*>(As[buf]) + r * 256 + byte) = sv;
    }
  };

  const int l  = tid & 63;
  const int w  = tid >> 6;
  const int wr = w >> 1, wc = w & 1;
  const int lr = l & 15;
  const int lk = l >> 4;

  const int arow0 = wr * 32 + lr;
  const int arow1 = arow0 + 16;
  const int ab0 = arow0 * 256, rx0 = (arow0 & 7) << 4;
  const int ab1 = arow1 * 256, rx1 = (arow1 & 7) << 4;

  const short* bB0 = WT + (size_t)(wc * 64 +  0 + lr) * 512 + lk * 8;
  const short* bB1 = WT + (size_t)(wc * 64 + 16 + lr) * 512 + lk * 8;
  const short* bB2 = WT + (size_t)(wc * 64 + 32 + lr) * 512 + lk * 8;
  const short* bB3 = WT + (size_t)(wc * 64 + 48 + lr) * 512 + lk * 8;

  f32x4 acc[2][4] = {};

  issue_loads(0);
  write_lds(0);
  __syncthreads();

#pragma unroll
  for (int kbidx = 0; kbidx < 4; ++kbidx) {
    const int cur = kbidx & 1;
    if (kbidx < 3) issue_loads((kbidx + 1) * 128);

    const char* base = reinterpret_cast<const char*>(As[cur]);
#pragma unroll
    for (int ks = 0; ks < 4; ++ks) {
      const int kbyte = ks * 64 + lk * 16;
      const short8 a0 = *reinterpret_cast<const short8*>(base + ab0 + (kbyte ^ rx0));
      const short8 a1 = *reinterpret_cast<const short8*>(base + ab1 + (kbyte ^ rx1));
      const int ko = kbidx * 128 + ks * 32;
      const short8 bb0 = *reinterpret_cast<const short8*>(bB0 + ko);
      const short8 bb1 = *reinterpret_cast<const short8*>(bB1 + ko);
      const short8 bb2 = *reinterpret_cast<const short8*>(bB2 + ko);
      const short8 bb3 = *reinterpret_cast<const short8*>(bB3 + ko);
      acc[0][0] = __builtin_amdgcn_mfma_f32_16x16x32_bf16(a0, bb0, acc[0][0], 0, 0, 0);
      acc[0][1] = __builtin_amdgcn_mfma_f32_16x16x32_bf16(a0, bb1, acc[0][1], 0, 0, 0);
      acc[0][2] = __builtin_amdgcn_mfma_f32_16x16x32_bf16(a0, bb2, acc[0][2], 0, 0, 0);
      acc[0][3] = __builtin_amdgcn_mfma_f32_16x16x32_bf16(a0, bb3, acc[0][3], 0, 0, 0);
      acc[1][0] = __builtin_amdgcn_mfma_f32_16x16x32_bf16(a1, bb0, acc[1][0], 0, 0, 0);
      acc[1][1] = __builtin_amdgcn_mfma_f32_16x16x32_bf16(a1, bb1, acc[1][1], 0, 0, 0);
      acc[1][2] = __builtin_amdgcn_mfma_f32_16x16x32_bf16(a1, bb2, acc[1][2], 0, 0, 0);
      acc[1][3] = __builtin_amdgcn_mfma_f32_16x16x32_bf16(a1, bb3, acc[1][3], 0, 0, 0);
    }

    if (kbidx < 3) {
      write_lds(cur ^ 1);
      __syncthreads();
    }
  }

#pragma unroll
  for (int m = 0; m < 2; ++m) {
    const int rbase = row0 + wr * 32 + m * 16 + (l >> 4) * 4;
#pragma unroll
    for (int j = 0; j < 4; ++j) {
      const int row = rbase + j;
      if (row < N_NODES) {
        const float sc = dinv[row];  // prescale: xwb = xw * dinv[row]
        unsigned short* o = &xwb[(size_t)row * OUT_DIM + wc * 64 + lr];
        o[0]  = (unsigned short)f2bf(acc[m][0][j] * sc);
        o[16] = (unsigned short)f2bf(acc[m][1][j] * sc);
        o[32] = (unsigned short)f2bf(acc[m][2][j] * sc);
        o[48] = (unsigned short)f2bf(acc[m][3][j] * sc);
      }
    }
  }
}

// ========== atomic-free edge grouping: 2-level binning, LDS-only atomics ====

// A1: per-block LDS histogram of bin = col>>8
__global__ __launch_bounds__(256) void bin_count(const int* __restrict__ ecol,
                                                 int* __restrict__ blkhist) {
  __shared__ int hist[NBINS];
  const int blk = blockIdx.x, tid = threadIdx.x;
  for (int i = tid; i < NBINS; i += 256) hist[i] = 0;
  __syncthreads();
  const int e0 = blk * CHUNK, e1 = e0 + CHUNK;
  for (int e = e0 + tid; e < e1; e += 256) atomicAdd(&hist[ecol[e] >> 8], 1);
  __syncthreads();
  for (int i = tid; i < NBINS; i += 256) blkhist[(size_t)blk * NBINS + i] = hist[i];
}

// A2a: per-bin exclusive scan over the NB block partials (in place)
__global__ __launch_bounds__(1024) void scan_blkhist(int* __restrict__ blkhist,
                                                     int* __restrict__ bintot) {
  __shared__ int sh[NB];
  const int bin = blockIdx.x, t = threadIdx.x;
  const int v = blkhist[(size_t)t * NBINS + bin];
  sh[t] = v;
  __syncthreads();
  for (int d = 1; d < NB; d <<= 1) {
    const int tv = (t >= d) ? sh[t - d] : 0;
    __syncthreads();
    sh[t] += tv;
    __syncthreads();
  }
  blkhist[(size_t)t * NBINS + bin] = sh[t] - v;  // exclusive prefix over blocks
  if (t == NB - 1) bintot[bin] = sh[t];
}

// A2b: exclusive scan over bin totals
__global__ __launch_bounds__(512) void scan_bins(const int* __restrict__ bintot,
                                                 int* __restrict__ binbase) {
  __shared__ int sh[512];
  const int t = threadIdx.x;
  const int v = (t < NBINS) ? bintot[t] : 0;
  sh[t] = v;
  __syncthreads();
  for (int d = 1; d < 512; d <<= 1) {
    const int tv = (t >= d) ? sh[t - d] : 0;
    __syncthreads();
    sh[t] += tv;
    __syncthreads();
  }
  if (t < NBINS) binbase[t] = sh[t] - v;
  if (t == NBINS - 1) binbase[NBINS] = sh[t];
}

// A3: scatter packed (local_col<<24 | row) into bin-segmented benc
__global__ __launch_bounds__(256) void bin_scatter(const int* __restrict__ erow,
                                                   const int* __restrict__ ecol,
                                                   const int* __restrict__ blkhist,
                                                   const int* __restrict__ binbase,
                                                   unsigned* __restrict__ benc) {
  __shared__ int cur[NBINS];
  const int blk = blockIdx.x, tid = threadIdx.x;
  for (int i = tid; i < NBINS; i += 256)
    cur[i] = binbase[i] + blkhist[(size_t)blk * NBINS + i];
  __syncthreads();
  const int e0 = blk * CHUNK, e1 = e0 + CHUNK;
  for (int e = e0 + tid; e < e1; e += 256) {
    const int c = ecol[e];
    const unsigned enc = (unsigned)erow[e] | ((unsigned)(c & 255) << 24);
    const int p = atomicAdd(&cur[c >> 8], 1);
    benc[p] = enc;
  }
}

// B: per-bin CSR build — offs, dinv, brow (one block per 256-node bin)
__global__ __launch_bounds__(256) void bin_build(const unsigned* __restrict__ benc,
                                                 const int* __restrict__ binbase,
                                                 int* __restrict__ brow,
                                                 int* __restrict__ offs,
                                                 float* __restrict__ dinv) {
  __shared__ int hist[256];
  __shared__ int sh[256];
  __shared__ int cur[256];
  const int b = blockIdx.x, tid = threadIdx.x;
  const int e0 = binbase[b], e1 = binbase[b + 1];
  hist[tid] = 0;
  __syncthreads();
  for (int e = e0 + tid; e < e1; e += 256) atomicAdd(&hist[benc[e] >> 24], 1);
  __syncthreads();
  const int d0 = hist[tid];
  sh[tid] = d0;
  __syncthreads();
  for (int d = 1; d < 256; d <<= 1) {
    const int tv = (tid >= d) ? sh[tid - d] : 0;
    __syncthreads();
    sh[tid] += tv;
    __syncthreads();
  }
  const int myoff = e0 + sh[tid] - d0;  // global CSR offset for node (b<<8)+tid
  cur[tid] = myoff;
  const int node = (b << 8) + tid;
  if (node < N_NODES) {
    offs[node] = myoff;
    dinv[node] = rsqrtf((float)d0 + 1.0f);
  }
  if (b == NBINS - 1 && tid == 255) offs[N_NODES] = e1;
  __syncthreads();
  for (int e = e0 + tid; e < e1; e += 256) {
    const unsigned v = benc[e];
    const int p = atomicAdd(&cur[v >> 24], 1);
    brow[p] = (int)(v & 0x00FFFFFFu);
  }
}

// ---------------- gather: one wave per destination node (prescaled bf16) ---
__global__ __launch_bounds__(256) void gather_out(const unsigned short* __restrict__ xwb,
                                                  const float* __restrict__ dinv,
                                                  const int* __restrict__ offs,
                                                  const int* __restrict__ brow,
                                                  const float* __restrict__ bias,
                                                  float* __restrict__ out) {
  const int lane = threadIdx.x & 63;
  const int node = blockIdx.x * (blockDim.x >> 6) + (threadIdx.x >> 6);
  if (node >= N_NODES) return;
  const float di = dinv[node];
  const int c0 = lane * 2;

  auto ld2 = [&](int r) -> float2 {
    const unsigned v = *reinterpret_cast<const unsigned*>(&xwb[(size_t)r * OUT_DIM + c0]);
    float2 f;
    f.x = __builtin_bit_cast(float, v << 16);
    f.y = __builtin_bit_cast(float, v & 0xFFFF0000u);
    return f;
  };

  float2 acc = ld2(node);  // self-loop: di * scaled[node] = di^2 * xw[node]

  int e = offs[node];
  const int e1 = offs[node + 1];
  for (; e + 8 <= e1; e += 8) {
    const int r0 = brow[e],     r1 = brow[e + 1], r2 = brow[e + 2], r3 = brow[e + 3];
    const int r4 = brow[e + 4], r5 = brow[e + 5], r6 = brow[e + 6], r7 = brow[e + 7];
    const float2 v0 = ld2(r0), v1 = ld2(r1), v2 = ld2(r2), v3 = ld2(r3);
    const float2 v4 = ld2(r4), v5 = ld2(r5), v6 = ld2(r6), v7 = ld2(r7);
    acc.x += ((v0.x + v1.x) + (v2.x + v3.x)) + ((v4.x + v5.x) + (v6.x + v7.x));
    acc.y += ((v0.y + v1.y) + (v2.y + v3.y)) + ((v4.y + v5.y) + (v6.y + v7.y));
  }
  for (; e < e1; ++e) {
    const float2 v = ld2(brow[e]);
    acc.x += v.x;
    acc.y += v.y;
  }

  const float2 bb = *reinterpret_cast<const float2*>(&bias[c0]);
  float2 o;
  o.x = acc.x * di + bb.x;
  o.y = acc.y * di + bb.y;
  *reinterpret_cast<float2*>(&out[(size_t)node * OUT_DIM + c0]) = o;
}

extern "C" void kernel_launch(void* const* d_in, const int* in_sizes, int n_in,
                              void* d_out, int out_size, void* d_ws, size_t ws_size,
                              hipStream_t stream) {
  const float* x    = (const float*)d_in[0];
  const int*   eidx = (const int*)d_in[1];
  const float* W    = (const float*)d_in[2];
  const float* b    = (const float*)d_in[3];
  float* out = (float*)d_out;

  const int* erow = eidx;            // sources
  const int* ecol = eidx + N_EDGES;  // destinations

  char* ws = (char*)d_ws;
  size_t off = 0;
  auto alloc = [&](size_t bytes) -> void* {
    void* p = ws + off;
    off = (off + bytes + 255) & ~(size_t)255;
    return p;
  };
  unsigned short* xwb = (unsigned short*)alloc((size_t)N_NODES * OUT_DIM * sizeof(short)); // 25.6MB
  short* WT      = (short*)alloc((size_t)OUT_DIM * IN_DIM * sizeof(short));    // 128KB
  float* dinv    = (float*)alloc((size_t)N_NODES * sizeof(float));             // 400KB
  int*   offs    = (int*)alloc((size_t)(N_NODES + 1) * sizeof(int));           // 400KB
  int*   blkhist = (int*)alloc((size_t)NB * NBINS * sizeof(int));              // 1.6MB
  int*   bintot  = (int*)alloc((size_t)NBINS * sizeof(int));
  int*   binbase = (int*)alloc((size_t)(NBINS + 1) * sizeof(int));
  int*   brow    = (int*)alloc((size_t)N_EDGES * sizeof(int));                 // 12.8MB
  unsigned* benc = (unsigned*)alloc((size_t)N_EDGES * sizeof(unsigned));       // 12.8MB

  cast_WT<<<256, 256, 0, stream>>>(W, WT);

  bin_count<<<NB, 256, 0, stream>>>(ecol, blkhist);
  scan_blkhist<<<NBINS, NB, 0, stream>>>(blkhist, bintot);
  scan_bins<<<1, 512, 0, stream>>>(bintot, binbase);
  bin_scatter<<<NB, 256, 0, stream>>>(erow, ecol, blkhist, binbase, benc);
  bin_build<<<NBINS, 256, 0, stream>>>(benc, binbase, brow, offs, dinv);

  gemm_mfma<<<(N_NODES + 63) / 64, 256, 0, stream>>>(x, WT, dinv, xwb);
  gather_out<<<(N_NODES + 3) / 4, 256, 0, stream>>>(xwb, dinv, offs, brow, b, out);
}

// Round 8
// 299.716 us; speedup vs baseline: 3.6070x; 1.0079x over previous
//
#include <hip/hip_runtime.h>

using short8 = __attribute__((ext_vector_type(8))) short;
using f32x4  = __attribute__((ext_vector_type(4))) float;

static constexpr int N_NODES = 100000;
static constexpr int N_EDGES = 3200000;
static constexpr int IN_DIM  = 512;
static constexpr int OUT_DIM = 128;
static constexpr int NBINS   = (N_NODES + 255) / 256;  // 391 bins of 256 nodes
static constexpr int NB      = 1024;                   // binning blocks
static constexpr int CHUNK   = N_EDGES / NB;           // 3125 edges/block (exact)

__device__ __forceinline__ short f2bf(float f) {
  unsigned u = __builtin_bit_cast(unsigned, f);
  u = (u + 0x7FFFu + ((u >> 16) & 1u)) >> 16;  // RNE
  return (short)u;
}

// ---------------- W [512][128] f32  ->  WT [128][512] bf16 ----------------
__global__ __launch_bounds__(256) void cast_WT(const float* __restrict__ W,
                                               short* __restrict__ WT) {
  const int idx = blockIdx.x * 256 + threadIdx.x;  // 65536 total
  const int c = idx >> 9, k = idx & 511;
  WT[(size_t)c * 512 + k] = f2bf(W[(size_t)k * 128 + c]);
}

// ---------------- MFMA GEMM: xwb = (x @ W) * dinv[row]  (bf16 out) --------
// BM=64, BK=64, 8 K-steps, depth-2 register prefetch, dbuf 2x8KB LDS.
// Per step t: issue loads(t+2) -> 16 MFMA/wave on buf[t&1] -> cast+write(t+1)
// -> barrier.
__global__ __launch_bounds__(256) void gemm_mfma(const float* __restrict__ x,
                                                 const short* __restrict__ WT,
                                                 const float* __restrict__ dinv,
                                                 unsigned short* __restrict__ xwb) {
  __shared__ short As[2][64 * 64];  // 2 x 8KB, row=128B, byte^((row&7)<<4)
  const int tid  = threadIdx.x;
  const int row0 = blockIdx.x * 64;

  float4 pf0[4], pf1[4];  // two in-flight tiles (static indexing only)

  auto issue = [&](int kb, float4* pf) {
#pragma unroll
    for (int c = 0; c < 2; ++c) {
      const int flat = c * 2048 + tid * 8;  // float idx in 64x64 tile
      const int r = flat >> 6;
      const int k = flat & 63;
      const int row = row0 + r;
      if (row < N_NODES) {
        const float* s = &x[(size_t)row * IN_DIM + kb + k];
        pf[c * 2]     = *reinterpret_cast<const float4*>(s);
        pf[c * 2 + 1] = *reinterpret_cast<const float4*>(s + 4);
      } else {
        pf[c * 2]     = make_float4(0.f, 0.f, 0.f, 0.f);
        pf[c * 2 + 1] = make_float4(0.f, 0.f, 0.f, 0.f);
      }
    }
  };

  auto wlds = [&](const float4* pf, int buf) {
#pragma unroll
    for (int c = 0; c < 2; ++c) {
      const int flat = c * 2048 + tid * 8;
      const int r = flat >> 6;
      const int k = flat & 63;
      const float4 f0 = pf[c * 2], f1 = pf[c * 2 + 1];
      short8 sv;
      sv[0] = f2bf(f0.x); sv[1] = f2bf(f0.y); sv[2] = f2bf(f0.z); sv[3] = f2bf(f0.w);
      sv[4] = f2bf(f1.x); sv[5] = f2bf(f1.y); sv[6] = f2bf(f1.z); sv[7] = f2bf(f1.w);
      const int byte = (k * 2) ^ ((r & 7) << 4);
      *reinterpret_cast<short8*>(reinterpret_cast<char*>(As[buf]) + r * 128 + byte) = sv;
    }
  };

  const int l  = tid & 63;
  const int w  = tid >> 6;
  const int wr = w >> 1, wc = w & 1;
  const int lr = l & 15;
  const int lk = l >> 4;

  const int arow0 = wr * 32 + lr;
  const int arow1 = arow0 + 16;
  const int ab0 = arow0 * 128, rx0 = (arow0 & 7) << 4;
  const int ab1 = arow1 * 128, rx1 = (arow1 & 7) << 4;

  const short* bB0 = WT + (size_t)(wc * 64 +  0 + lr) * 512 + lk * 8;
  const short* bB1 = WT + (size_t)(wc * 64 + 16 + lr) * 512 + lk * 8;
  const short* bB2 = WT + (size_t)(wc * 64 + 32 + lr) * 512 + lk * 8;
  const short* bB3 = WT + (size_t)(wc * 64 + 48 + lr) * 512 + lk * 8;

  f32x4 acc[2][4] = {};

  auto compute = [&](int buf, int kbidx) {
    const char* base = reinterpret_cast<const char*>(As[buf]);
#pragma unroll
    for (int ks = 0; ks < 2; ++ks) {
      const int kbyte = ks * 64 + lk * 16;
      const short8 a0 = *reinterpret_cast<const short8*>(base + ab0 + (kbyte ^ rx0));
      const short8 a1 = *reinterpret_cast<const short8*>(base + ab1 + (kbyte ^ rx1));
      const int ko = kbidx * 64 + ks * 32;
      const short8 bb0 = *reinterpret_cast<const short8*>(bB0 + ko);
      const short8 bb1 = *reinterpret_cast<const short8*>(bB1 + ko);
      const short8 bb2 = *reinterpret_cast<const short8*>(bB2 + ko);
      const short8 bb3 = *reinterpret_cast<const short8*>(bB3 + ko);
      acc[0][0] = __builtin_amdgcn_mfma_f32_16x16x32_bf16(a0, bb0, acc[0][0], 0, 0, 0);
      acc[0][1] = __builtin_amdgcn_mfma_f32_16x16x32_bf16(a0, bb1, acc[0][1], 0, 0, 0);
      acc[0][2] = __builtin_amdgcn_mfma_f32_16x16x32_bf16(a0, bb2, acc[0][2], 0, 0, 0);
      acc[0][3] = __builtin_amdgcn_mfma_f32_16x16x32_bf16(a0, bb3, acc[0][3], 0, 0, 0);
      acc[1][0] = __builtin_amdgcn_mfma_f32_16x16x32_bf16(a1, bb0, acc[1][0], 0, 0, 0);
      acc[1][1] = __builtin_amdgcn_mfma_f32_16x16x32_bf16(a1, bb1, acc[1][1], 0, 0, 0);
      acc[1][2] = __builtin_amdgcn_mfma_f32_16x16x32_bf16(a1, bb2, acc[1][2], 0, 0, 0);
      acc[1][3] = __builtin_amdgcn_mfma_f32_16x16x32_bf16(a1, bb3, acc[1][3], 0, 0, 0);
    }
  };

  // prologue: tiles 0 and 1 in flight; tile 0 -> buf0
  issue(0, pf0);
  issue(64, pf1);
  wlds(pf0, 0);
  __syncthreads();

  // t=0: compute buf0(k0); issue k2->pf0; write pf1(k1)->buf1
  compute(0, 0); issue(128, pf0); wlds(pf1, 1); __syncthreads();
  // t=1
  compute(1, 1); issue(192, pf1); wlds(pf0, 0); __syncthreads();
  // t=2
  compute(0, 2); issue(256, pf0); wlds(pf1, 1); __syncthreads();
  // t=3
  compute(1, 3); issue(320, pf1); wlds(pf0, 0); __syncthreads();
  // t=4
  compute(0, 4); issue(384, pf0); wlds(pf1, 1); __syncthreads();
  // t=5
  compute(1, 5); issue(448, pf1); wlds(pf0, 0); __syncthreads();
  // t=6 (no more issues)
  compute(0, 6); wlds(pf1, 1); __syncthreads();
  // t=7
  compute(1, 7);

#pragma unroll
  for (int m = 0; m < 2; ++m) {
    const int rbase = row0 + wr * 32 + m * 16 + (l >> 4) * 4;
#pragma unroll
    for (int j = 0; j < 4; ++j) {
      const int row = rbase + j;
      if (row < N_NODES) {
        const float sc = dinv[row];  // prescale: xwb = xw * dinv[row]
        unsigned short* o = &xwb[(size_t)row * OUT_DIM + wc * 64 + lr];
        o[0]  = (unsigned short)f2bf(acc[m][0][j] * sc);
        o[16] = (unsigned short)f2bf(acc[m][1][j] * sc);
        o[32] = (unsigned short)f2bf(acc[m][2][j] * sc);
        o[48] = (unsigned short)f2bf(acc[m][3][j] * sc);
      }
    }
  }
}

// ========== atomic-free edge grouping: 2-level binning, LDS-only atomics ====

// A1: per-block LDS histogram of bin = col>>8
__global__ __launch_bounds__(256) void bin_count(const int* __restrict__ ecol,
                                                 int* __restrict__ blkhist) {
  __shared__ int hist[NBINS];
  const int blk = blockIdx.x, tid = threadIdx.x;
  for (int i = tid; i < NBINS; i += 256) hist[i] = 0;
  __syncthreads();
  const int e0 = blk * CHUNK, e1 = e0 + CHUNK;
  for (int e = e0 + tid; e < e1; e += 256) atomicAdd(&hist[ecol[e] >> 8], 1);
  __syncthreads();
  for (int i = tid; i < NBINS; i += 256) blkhist[(size_t)blk * NBINS + i] = hist[i];
}

// A2a: per-bin exclusive scan over the NB block partials (in place)
__global__ __launch_bounds__(1024) void scan_blkhist(int* __restrict__ blkhist,
                                                     int* __restrict__ bintot) {
  __shared__ int sh[NB];
  const int bin = blockIdx.x, t = threadIdx.x;
  const int v = blkhist[(size_t)t * NBINS + bin];
  sh[t] = v;
  __syncthreads();
  for (int d = 1; d < NB; d <<= 1) {
    const int tv = (t >= d) ? sh[t - d] : 0;
    __syncthreads();
    sh[t] += tv;
    __syncthreads();
  }
  blkhist[(size_t)t * NBINS + bin] = sh[t] - v;  // exclusive prefix over blocks
  if (t == NB - 1) bintot[bin] = sh[t];
}

// A2b: exclusive scan over bin totals
__global__ __launch_bounds__(512) void scan_bins(const int* __restrict__ bintot,
                                                 int* __restrict__ binbase) {
  __shared__ int sh[512];
  const int t = threadIdx.x;
  const int v = (t < NBINS) ? bintot[t] : 0;
  sh[t] = v;
  __syncthreads();
  for (int d = 1; d < 512; d <<= 1) {
    const int tv = (t >= d) ? sh[t - d] : 0;
    __syncthreads();
    sh[t] += tv;
    __syncthreads();
  }
  if (t < NBINS) binbase[t] = sh[t] - v;
  if (t == NBINS - 1) binbase[NBINS] = sh[t];
}

// A3: scatter packed (local_col<<24 | row) into bin-segmented benc
__global__ __launch_bounds__(256) void bin_scatter(const int* __restrict__ erow,
                                                   const int* __restrict__ ecol,
                                                   const int* __restrict__ blkhist,
                                                   const int* __restrict__ binbase,
                                                   unsigned* __restrict__ benc) {
  __shared__ int cur[NBINS];
  const int blk = blockIdx.x, tid = threadIdx.x;
  for (int i = tid; i < NBINS; i += 256)
    cur[i] = binbase[i] + blkhist[(size_t)blk * NBINS + i];
  __syncthreads();
  const int e0 = blk * CHUNK, e1 = e0 + CHUNK;
  for (int e = e0 + tid; e < e1; e += 256) {
    const int c = ecol[e];
    const unsigned enc = (unsigned)erow[e] | ((unsigned)(c & 255) << 24);
    const int p = atomicAdd(&cur[c >> 8], 1);
    benc[p] = enc;
  }
}

// B: per-bin CSR build — offs, dinv, brow (one block per 256-node bin)
__global__ __launch_bounds__(256) void bin_build(const unsigned* __restrict__ benc,
                                                 const int* __restrict__ binbase,
                                                 int* __restrict__ brow,
                                                 int* __restrict__ offs,
                                                 float* __restrict__ dinv) {
  __shared__ int hist[256];
  __shared__ int sh[256];
  __shared__ int cur[256];
  const int b = blockIdx.x, tid = threadIdx.x;
  const int e0 = binbase[b], e1 = binbase[b + 1];
  hist[tid] = 0;
  __syncthreads();
  for (int e = e0 + tid; e < e1; e += 256) atomicAdd(&hist[benc[e] >> 24], 1);
  __syncthreads();
  const int d0 = hist[tid];
  sh[tid] = d0;
  __syncthreads();
  for (int d = 1; d < 256; d <<= 1) {
    const int tv = (tid >= d) ? sh[tid - d] : 0;
    __syncthreads();
    sh[tid] += tv;
    __syncthreads();
  }
  const int myoff = e0 + sh[tid] - d0;  // global CSR offset for node (b<<8)+tid
  cur[tid] = myoff;
  const int node = (b << 8) + tid;
  if (node < N_NODES) {
    offs[node] = myoff;
    dinv[node] = rsqrtf((float)d0 + 1.0f);
  }
  if (b == NBINS - 1 && tid == 255) offs[N_NODES] = e1;
  __syncthreads();
  for (int e = e0 + tid; e < e1; e += 256) {
    const unsigned v = benc[e];
    const int p = atomicAdd(&cur[v >> 24], 1);
    brow[p] = (int)(v & 0x00FFFFFFu);
  }
}

// ---------------- gather: one wave per destination node (prescaled bf16) ---
__global__ __launch_bounds__(256) void gather_out(const unsigned short* __restrict__ xwb,
                                                  const float* __restrict__ dinv,
                                                  const int* __restrict__ offs,
                                                  const int* __restrict__ brow,
                                                  const float* __restrict__ bias,
                                                  float* __restrict__ out) {
  const int lane = threadIdx.x & 63;
  const int node = blockIdx.x * (blockDim.x >> 6) + (threadIdx.x >> 6);
  if (node >= N_NODES) return;
  const float di = dinv[node];
  const int c0 = lane * 2;

  auto ld2 = [&](int r) -> float2 {
    const unsigned v = *reinterpret_cast<const unsigned*>(&xwb[(size_t)r * OUT_DIM + c0]);
    float2 f;
    f.x = __builtin_bit_cast(float, v << 16);
    f.y = __builtin_bit_cast(float, v & 0xFFFF0000u);
    return f;
  };

  float2 acc = ld2(node);  // self-loop: di * scaled[node] = di^2 * xw[node]

  int e = offs[node];
  const int e1 = offs[node + 1];
  for (; e + 8 <= e1; e += 8) {
    const int r0 = brow[e],     r1 = brow[e + 1], r2 = brow[e + 2], r3 = brow[e + 3];
    const int r4 = brow[e + 4], r5 = brow[e + 5], r6 = brow[e + 6], r7 = brow[e + 7];
    const float2 v0 = ld2(r0), v1 = ld2(r1), v2 = ld2(r2), v3 = ld2(r3);
    const float2 v4 = ld2(r4), v5 = ld2(r5), v6 = ld2(r6), v7 = ld2(r7);
    acc.x += ((v0.x + v1.x) + (v2.x + v3.x)) + ((v4.x + v5.x) + (v6.x + v7.x));
    acc.y += ((v0.y + v1.y) + (v2.y + v3.y)) + ((v4.y + v5.y) + (v6.y + v7.y));
  }
  for (; e < e1; ++e) {
    const float2 v = ld2(brow[e]);
    acc.x += v.x;
    acc.y += v.y;
  }

  const float2 bb = *reinterpret_cast<const float2*>(&bias[c0]);
  float2 o;
  o.x = acc.x * di + bb.x;
  o.y = acc.y * di + bb.y;
  *reinterpret_cast<float2*>(&out[(size_t)node * OUT_DIM + c0]) = o;
}

extern "C" void kernel_launch(void* const* d_in, const int* in_sizes, int n_in,
                              void* d_out, int out_size, void* d_ws, size_t ws_size,
                              hipStream_t stream) {
  const float* x    = (const float*)d_in[0];
  const int*   eidx = (const int*)d_in[1];
  const float* W    = (const float*)d_in[2];
  const float* b    = (const float*)d_in[3];
  float* out = (float*)d_out;

  const int* erow = eidx;            // sources
  const int* ecol = eidx + N_EDGES;  // destinations

  char* ws = (char*)d_ws;
  size_t off = 0;
  auto alloc = [&](size_t bytes) -> void* {
    void* p = ws + off;
    off = (off + bytes + 255) & ~(size_t)255;
    return p;
  };
  unsigned short* xwb = (unsigned short*)alloc((size_t)N_NODES * OUT_DIM * sizeof(short)); // 25.6MB
  short* WT      = (short*)alloc((size_t)OUT_DIM * IN_DIM * sizeof(short));    // 128KB
  float* dinv    = (float*)alloc((size_t)N_NODES * sizeof(float));             // 400KB
  int*   offs    = (int*)alloc((size_t)(N_NODES + 1) * sizeof(int));           // 400KB
  int*   blkhist = (int*)alloc((size_t)NB * NBINS * sizeof(int));              // 1.6MB
  int*   bintot  = (int*)alloc((size_t)NBINS * sizeof(int));
  int*   binbase = (int*)alloc((size_t)(NBINS + 1) * sizeof(int));
  int*   brow    = (int*)alloc((size_t)N_EDGES * sizeof(int));                 // 12.8MB
  unsigned* benc = (unsigned*)alloc((size_t)N_EDGES * sizeof(unsigned));       // 12.8MB

  cast_WT<<<256, 256, 0, stream>>>(W, WT);

  bin_count<<<NB, 256, 0, stream>>>(ecol, blkhist);
  scan_blkhist<<<NBINS, NB, 0, stream>>>(blkhist, bintot);
  scan_bins<<<1, 512, 0, stream>>>(bintot, binbase);
  bin_scatter<<<NB, 256, 0, stream>>>(erow, ecol, blkhist, binbase, benc);
  bin_build<<<NBINS, 256, 0, stream>>>(benc, binbase, brow, offs, dinv);

  gemm_mfma<<<(N_NODES + 63) / 64, 256, 0, stream>>>(x, WT, dinv, xwb);
  gather_out<<<(N_NODES + 3) / 4, 256, 0, stream>>>(xwb, dinv, offs, brow, b, out);
}